// Round 1
// baseline (444.582 us; speedup 1.0000x reference)
//
#include <hip/hip_runtime.h>

#define HD 128          // hidden dim (fixed by problem)
#define TR 32           // rows per GEMM block

// ---------------------------------------------------------------- row_ptr ----
// dst is sorted; rp[i] = lower_bound(dst, i), rp[N] = E.
__global__ __launch_bounds__(256) void k_rowptr(const int* __restrict__ dst, int E,
                                                int* __restrict__ rp, int N) {
    int i = blockIdx.x * blockDim.x + threadIdx.x;
    if (i > N) return;
    int lo = 0, hi = E;
    while (lo < hi) {
        int mid = (lo + hi) >> 1;
        if (dst[mid] < i) lo = mid + 1; else hi = mid;
    }
    rp[i] = lo;
}

// ---------------------------------------------------------------- gather -----
// h[row][:] = emb[node_ids[row]][:]; 32 threads/row, float4 each.
__global__ __launch_bounds__(256) void k_gather(const int* __restrict__ ids,
                                                const float* __restrict__ emb,
                                                float* __restrict__ h, int N) {
    int idx = blockIdx.x * blockDim.x + threadIdx.x;
    int row = idx >> 5;
    if (row >= N) return;
    int c = (idx & 31) * 4;
    *(float4*)&h[(size_t)row * HD + c] =
        *(const float4*)&emb[(size_t)ids[row] * HD + c];
}

// ------------------------------------------------------------- GEMM pieces ---
__device__ __forceinline__ void stage_tile(const float* __restrict__ g, float* hs,
                                           int rbase, int nrows, int tid) {
#pragma unroll
    for (int i = 0; i < 4; ++i) {
        int idx = tid * 4 + i * 1024;          // covers TR*HD = 4096 floats
        int r = idx >> 7;
        int gr = rbase + r;
        float4 v = make_float4(0.f, 0.f, 0.f, 0.f);
        if (gr < nrows) v = *(const float4*)&g[(size_t)gr * HD + (idx & 127)];
        *(float4*)&hs[idx] = v;
    }
}

// acc[4rows][4cols] += hs(tile) @ W   ; thread owns rows rg..rg+3, cols jq..jq+3
__device__ __forceinline__ void mm_accum(const float* hs, const float* __restrict__ W,
                                         int jq, int rg, float (&acc)[4][4]) {
    for (int k = 0; k < HD; k += 4) {
        const float4 w0 = *(const float4*)&W[(k + 0) * HD + jq];
        const float4 w1 = *(const float4*)&W[(k + 1) * HD + jq];
        const float4 w2 = *(const float4*)&W[(k + 2) * HD + jq];
        const float4 w3 = *(const float4*)&W[(k + 3) * HD + jq];
#pragma unroll
        for (int r = 0; r < 4; ++r) {
            const float4 a = *(const float4*)&hs[(rg + r) * HD + k];
            acc[r][0] += a.x * w0.x + a.y * w1.x + a.z * w2.x + a.w * w3.x;
            acc[r][1] += a.x * w0.y + a.y * w1.y + a.z * w2.y + a.w * w3.y;
            acc[r][2] += a.x * w0.z + a.y * w1.z + a.z * w2.z + a.w * w3.z;
            acc[r][3] += a.x * w0.w + a.y * w1.w + a.z * w2.w + a.w * w3.w;
        }
    }
}

// m = relu(h @ W + b)
__global__ __launch_bounds__(256) void k_gemm_pool(const float* __restrict__ hin,
                                                   const float* __restrict__ W,
                                                   const float* __restrict__ bias,
                                                   float* __restrict__ out, int nrows) {
    __shared__ float hs[TR * HD];
    const int tid = threadIdx.x;
    const int rbase = blockIdx.x * TR;
    stage_tile(hin, hs, rbase, nrows, tid);
    __syncthreads();

    const int jq = (tid & 31) * 4;
    const int rg = (tid >> 5) * 4;
    const float4 bv = *(const float4*)&bias[jq];
    float acc[4][4];
#pragma unroll
    for (int r = 0; r < 4; ++r) { acc[r][0] = bv.x; acc[r][1] = bv.y; acc[r][2] = bv.z; acc[r][3] = bv.w; }

    mm_accum(hs, W, jq, rg, acc);

#pragma unroll
    for (int r = 0; r < 4; ++r) {
        int gr = rbase + rg + r;
        if (gr < nrows) {
            float4 o = make_float4(fmaxf(acc[r][0], 0.f), fmaxf(acc[r][1], 0.f),
                                   fmaxf(acc[r][2], 0.f), fmaxf(acc[r][3], 0.f));
            *(float4*)&out[(size_t)gr * HD + jq] = o;
        }
    }
}

// out = h @ Wself + agg @ Wneigh + b   (no relu). Safe when out == h (tile staged first).
__global__ __launch_bounds__(256) void k_gemm_dual(const float* __restrict__ hin,
                                                   const float* __restrict__ agg,
                                                   const float* __restrict__ Wself,
                                                   const float* __restrict__ Wneigh,
                                                   const float* __restrict__ bias,
                                                   float* __restrict__ out, int nrows) {
    __shared__ float hs[TR * HD];
    const int tid = threadIdx.x;
    const int rbase = blockIdx.x * TR;
    const int jq = (tid & 31) * 4;
    const int rg = (tid >> 5) * 4;

    const float4 bv = *(const float4*)&bias[jq];
    float acc[4][4];
#pragma unroll
    for (int r = 0; r < 4; ++r) { acc[r][0] = bv.x; acc[r][1] = bv.y; acc[r][2] = bv.z; acc[r][3] = bv.w; }

    stage_tile(hin, hs, rbase, nrows, tid);
    __syncthreads();
    mm_accum(hs, Wself, jq, rg, acc);
    __syncthreads();                       // pass-1 LDS reads done before restage
    stage_tile(agg, hs, rbase, nrows, tid);
    __syncthreads();
    mm_accum(hs, Wneigh, jq, rg, acc);

#pragma unroll
    for (int r = 0; r < 4; ++r) {
        int gr = rbase + rg + r;
        if (gr < nrows) {
            float4 o = make_float4(acc[r][0], acc[r][1], acc[r][2], acc[r][3]);
            *(float4*)&out[(size_t)gr * HD + jq] = o;
        }
    }
}

// ---------------------------------------------------------------- segmax -----
__device__ __forceinline__ float4 max4(float4 a, float4 b) {
    return make_float4(fmaxf(a.x, b.x), fmaxf(a.y, b.y), fmaxf(a.z, b.z), fmaxf(a.w, b.w));
}

// agg[n][:] = max over e in [rp[n],rp[n+1]) of m[src[e]][:], init 0
// (valid because m = relu(...) >= 0 and DGL maps zero-in-degree -> 0).
// 8 nodes per 256-thread block, 32 lanes per node, float4 per lane.
__global__ __launch_bounds__(256) void k_segmax(const float* __restrict__ m,
                                                const int* __restrict__ src,
                                                const int* __restrict__ rp,
                                                float* __restrict__ agg, int N) {
    int node = blockIdx.x * 8 + (threadIdx.x >> 5);
    if (node >= N) return;
    int lane = (threadIdx.x & 31) * 4;
    int beg = rp[node], end = rp[node + 1];
    float4 acc = make_float4(0.f, 0.f, 0.f, 0.f);
    for (int e = beg; e < end; ++e) {
        int s = src[e];
        acc = max4(acc, *(const float4*)&m[(size_t)s * HD + lane]);
    }
    *(float4*)&agg[(size_t)node * HD + lane] = acc;
}

// ---------------------------------------------------------------- launch -----
extern "C" void kernel_launch(void* const* d_in, const int* in_sizes, int n_in,
                              void* d_out, int out_size, void* d_ws, size_t ws_size,
                              hipStream_t stream) {
    const int*   node_ids = (const int*)d_in[0];
    const int*   src      = (const int*)d_in[1];
    const int*   dst      = (const int*)d_in[2];
    const float* emb      = (const float*)d_in[3];
    const float* Wp1      = (const float*)d_in[4];
    const float* bp1      = (const float*)d_in[5];
    const float* Ws1      = (const float*)d_in[6];
    const float* Wn1      = (const float*)d_in[7];
    const float* b1       = (const float*)d_in[8];
    const float* Wp2      = (const float*)d_in[9];
    const float* bp2      = (const float*)d_in[10];
    const float* Ws2      = (const float*)d_in[11];
    const float* Wn2      = (const float*)d_in[12];
    const float* b2       = (const float*)d_in[13];
    float* out = (float*)d_out;

    const int N = in_sizes[0];
    const int E = in_sizes[1];

    char* ws = (char*)d_ws;
    int* rp = (int*)ws;
    size_t off = (((size_t)(N + 1) * 4) + 255) & ~(size_t)255;
    float* bufH = (float*)(ws + off);                 // h0 (layer-1 input)
    float* bufM = bufH + (size_t)N * HD;              // pooled messages m
    float* bufA = bufM + (size_t)N * HD;              // segment-max agg

    const int nb_gemm = (N + TR - 1) / TR;
    const int nb_seg  = (N + 7) / 8;

    k_rowptr<<<(N + 256) / 256, 256, 0, stream>>>(dst, E, rp, N);
    k_gather<<<(N * 32 + 255) / 256, 256, 0, stream>>>(node_ids, emb, bufH, N);

    // layer 1: h1 -> d_out
    k_gemm_pool<<<nb_gemm, 256, 0, stream>>>(bufH, Wp1, bp1, bufM, N);
    k_segmax  <<<nb_seg,  256, 0, stream>>>(bufM, src, rp, bufA, N);
    k_gemm_dual<<<nb_gemm, 256, 0, stream>>>(bufH, bufA, Ws1, Wn1, b1, out, N);

    // layer 2: reads d_out, final result in-place to d_out
    k_gemm_pool<<<nb_gemm, 256, 0, stream>>>(out, Wp2, bp2, bufM, N);
    k_segmax  <<<nb_seg,  256, 0, stream>>>(bufM, src, rp, bufA, N);
    k_gemm_dual<<<nb_gemm, 256, 0, stream>>>(out, bufA, Ws2, Wn2, b2, out, N);
}

// Round 2
// 250.686 us; speedup vs baseline: 1.7735x; 1.7735x over previous
//
#include <hip/hip_runtime.h>

#define HD 128

typedef __attribute__((ext_vector_type(8))) short short8;   // 8 bf16 in 4 VGPRs
typedef __attribute__((ext_vector_type(4))) float floatx4;  // MFMA accumulator

typedef unsigned short ushort_t;
typedef unsigned int uint_t;

// ---------------------------------------------------------------- helpers ----
__device__ __forceinline__ ushort_t f2b(float f) {          // fp32 -> bf16 RNE
    union { float f; uint_t u; } v; v.f = f;
    uint_t r = v.u + 0x7fff + ((v.u >> 16) & 1);
    return (ushort_t)(r >> 16);
}
__device__ __forceinline__ float b_lo(uint_t p) {           // low bf16 of a dword
    union { uint_t u; float f; } v; v.u = p << 16; return v.f;
}
__device__ __forceinline__ float b_hi(uint_t p) {           // high bf16 of a dword
    union { uint_t u; float f; } v; v.u = p & 0xffff0000u; return v.f;
}
__device__ __forceinline__ uint_t packb(float a, float b) { // both already bf16-exact
    union { float f; uint_t u; } x, y; x.f = a; y.f = b;
    return (x.u >> 16) | (y.u & 0xffff0000u);
}

// ---------------------------------------------------------------- row_ptr ----
__global__ __launch_bounds__(256) void k_rowptr(const int* __restrict__ dst, int E,
                                                int* __restrict__ rp, int N) {
    int i = blockIdx.x * blockDim.x + threadIdx.x;
    if (i > N) return;
    int lo = 0, hi = E;
    while (lo < hi) {
        int mid = (lo + hi) >> 1;
        if (dst[mid] < i) lo = mid + 1; else hi = mid;
    }
    rp[i] = lo;
}

// ---------------------------------------------------------------- gather -----
// h0_bf16[row][:] = bf16(emb[node_ids[row]][:]); 32 lanes/row, float4 -> ushort4.
__global__ __launch_bounds__(256) void k_gather(const int* __restrict__ ids,
                                                const float* __restrict__ emb,
                                                ushort_t* __restrict__ h, int N) {
    int idx = blockIdx.x * blockDim.x + threadIdx.x;
    int row = idx >> 5;
    if (row >= N) return;
    int c = (idx & 31) * 4;
    float4 v = *(const float4*)&emb[(size_t)ids[row] * HD + c];
    uint_t o0 = packb(b_lo(0), 0.f); // dummy to keep compiler quiet (unused)
    (void)o0;
    uint2 o;
    o.x = (uint_t)f2b(v.x) | ((uint_t)f2b(v.y) << 16);
    o.y = (uint_t)f2b(v.z) | ((uint_t)f2b(v.w) << 16);
    *(uint2*)&h[(size_t)row * HD + c] = o;
}

// ---------------------------------------------------------------- W pack -----
// Pack fp32 W[K=128][N=128] into B-fragment order for mfma_f32_16x16x32_bf16:
// Wpk[t*2048 + s*512 + l*8 + j] = bf16(W[(s*32 + (l>>4)*8 + j)*128 + t*16 + (l&15)])
// t = 16-col tile (0..7), s = K-step (0..3), l = lane (0..63), j = 0..7.
__global__ __launch_bounds__(256) void k_pack(const float* W0, const float* W1,
                                              const float* W2, const float* W3,
                                              const float* W4, const float* W5,
                                              ushort_t* __restrict__ out) {
    const float* Ws[6] = {W0, W1, W2, W3, W4, W5};
    int mat = blockIdx.x >> 6;                 // 64 blocks per matrix
    int o = ((blockIdx.x & 63) << 8) + threadIdx.x;  // 0..16383
    int j = o & 7, l = (o >> 3) & 63, s = (o >> 9) & 3, t = o >> 11;
    int k = s * 32 + ((l >> 4) & 3) * 8 + j;
    int n = t * 16 + (l & 15);
    out[(size_t)mat * 16384 + o] = f2b(Ws[mat][k * HD + n]);
}

// ---------------------------------------------------------- MFMA GEMM pool ---
// m = relu(h @ W + b), h/m bf16, W packed. 1 wave = 16 rows x 128 cols.
__global__ __launch_bounds__(256) void k_pool_mfma(const ushort_t* __restrict__ h,
                                                   const ushort_t* __restrict__ Wpk,
                                                   const float* __restrict__ bias,
                                                   ushort_t* __restrict__ m, int N) {
    int wave = blockIdx.x * 4 + (threadIdx.x >> 6);
    int row0 = wave * 16;
    if (row0 >= N) return;
    int l = threadIdx.x & 63;
    int ar = row0 + (l & 15);
    if (ar >= N) ar = N - 1;                   // safe clamp (N%16==0 -> no-op)
    int ac = (l >> 4) * 8;
    short8 a[4];
#pragma unroll
    for (int s = 0; s < 4; ++s)
        a[s] = *(const short8*)&h[(size_t)ar * HD + s * 32 + ac];

    int rbase = row0 + (l >> 4) * 4;
#pragma unroll
    for (int t = 0; t < 8; ++t) {
        floatx4 acc = {0.f, 0.f, 0.f, 0.f};
#pragma unroll
        for (int s = 0; s < 4; ++s) {
            short8 b = *(const short8*)&Wpk[(t * 4 + s) * 512 + l * 8];
            acc = __builtin_amdgcn_mfma_f32_16x16x32_bf16(a[s], b, acc, 0, 0, 0);
        }
        int col = t * 16 + (l & 15);
        float bv = bias[col];
#pragma unroll
        for (int r = 0; r < 4; ++r) {
            int gr = rbase + r;
            if (gr < N)
                m[(size_t)gr * HD + col] = f2b(fmaxf(acc[r] + bv, 0.f));
        }
    }
}

// ---------------------------------------------------------- MFMA GEMM dual ---
// out = h @ Wself + agg @ Wneigh + b.  F32OUT: write fp32 (final), else bf16.
template <bool F32OUT>
__global__ __launch_bounds__(256) void k_dual_mfma(const ushort_t* __restrict__ h,
                                                   const ushort_t* __restrict__ agg,
                                                   const ushort_t* __restrict__ WsPk,
                                                   const ushort_t* __restrict__ WnPk,
                                                   const float* __restrict__ bias,
                                                   void* __restrict__ outp, int N) {
    int wave = blockIdx.x * 4 + (threadIdx.x >> 6);
    int row0 = wave * 16;
    if (row0 >= N) return;
    int l = threadIdx.x & 63;
    int ar = row0 + (l & 15);
    if (ar >= N) ar = N - 1;
    int ac = (l >> 4) * 8;
    short8 ah[4], ag[4];
#pragma unroll
    for (int s = 0; s < 4; ++s) {
        ah[s] = *(const short8*)&h[(size_t)ar * HD + s * 32 + ac];
        ag[s] = *(const short8*)&agg[(size_t)ar * HD + s * 32 + ac];
    }

    int rbase = row0 + (l >> 4) * 4;
#pragma unroll
    for (int t = 0; t < 8; ++t) {
        floatx4 acc = {0.f, 0.f, 0.f, 0.f};
#pragma unroll
        for (int s = 0; s < 4; ++s) {
            short8 bs = *(const short8*)&WsPk[(t * 4 + s) * 512 + l * 8];
            acc = __builtin_amdgcn_mfma_f32_16x16x32_bf16(ah[s], bs, acc, 0, 0, 0);
        }
#pragma unroll
        for (int s = 0; s < 4; ++s) {
            short8 bn = *(const short8*)&WnPk[(t * 4 + s) * 512 + l * 8];
            acc = __builtin_amdgcn_mfma_f32_16x16x32_bf16(ag[s], bn, acc, 0, 0, 0);
        }
        int col = t * 16 + (l & 15);
        float bv = bias[col];
#pragma unroll
        for (int r = 0; r < 4; ++r) {
            int gr = rbase + r;
            if (gr < N) {
                float v = acc[r] + bv;
                if (F32OUT) ((float*)outp)[(size_t)gr * HD + col] = v;
                else        ((ushort_t*)outp)[(size_t)gr * HD + col] = f2b(v);
            }
        }
    }
}

// ---------------------------------------------------------------- segmax -----
// agg[n][:] = max(0, max_{e in [rp[n],rp[n+1])} m[src[e]][:])  (bf16 rows, 256B)
// 8 nodes/block, 32 lanes/node, 4 bf16 (8B) per lane; 2-edge unroll for MLP.
__global__ __launch_bounds__(256) void k_segmax(const ushort_t* __restrict__ m,
                                                const int* __restrict__ src,
                                                const int* __restrict__ rp,
                                                ushort_t* __restrict__ agg, int N) {
    int node = blockIdx.x * 8 + (threadIdx.x >> 5);
    if (node >= N) return;
    int lane = threadIdx.x & 31;
    int beg = rp[node], end = rp[node + 1];
    float a0 = 0.f, a1 = 0.f, a2 = 0.f, a3 = 0.f;
    float c0 = 0.f, c1 = 0.f, c2 = 0.f, c3 = 0.f;
    int e = beg;
    for (; e + 2 <= end; e += 2) {
        int s0 = src[e], s1 = src[e + 1];
        uint2 p = *(const uint2*)&m[(size_t)s0 * HD + lane * 4];
        uint2 q = *(const uint2*)&m[(size_t)s1 * HD + lane * 4];
        a0 = fmaxf(a0, b_lo(p.x)); a1 = fmaxf(a1, b_hi(p.x));
        a2 = fmaxf(a2, b_lo(p.y)); a3 = fmaxf(a3, b_hi(p.y));
        c0 = fmaxf(c0, b_lo(q.x)); c1 = fmaxf(c1, b_hi(q.x));
        c2 = fmaxf(c2, b_lo(q.y)); c3 = fmaxf(c3, b_hi(q.y));
    }
    if (e < end) {
        uint2 p = *(const uint2*)&m[(size_t)src[e] * HD + lane * 4];
        a0 = fmaxf(a0, b_lo(p.x)); a1 = fmaxf(a1, b_hi(p.x));
        a2 = fmaxf(a2, b_lo(p.y)); a3 = fmaxf(a3, b_hi(p.y));
    }
    a0 = fmaxf(a0, c0); a1 = fmaxf(a1, c1); a2 = fmaxf(a2, c2); a3 = fmaxf(a3, c3);
    uint2 o; o.x = packb(a0, a1); o.y = packb(a2, a3);
    *(uint2*)&agg[(size_t)node * HD + lane * 4] = o;
}

// ---------------------------------------------------------------- launch -----
extern "C" void kernel_launch(void* const* d_in, const int* in_sizes, int n_in,
                              void* d_out, int out_size, void* d_ws, size_t ws_size,
                              hipStream_t stream) {
    const int*   node_ids = (const int*)d_in[0];
    const int*   src      = (const int*)d_in[1];
    const int*   dst      = (const int*)d_in[2];
    const float* emb      = (const float*)d_in[3];
    const float* Wp1      = (const float*)d_in[4];
    const float* bp1      = (const float*)d_in[5];
    const float* Ws1      = (const float*)d_in[6];
    const float* Wn1      = (const float*)d_in[7];
    const float* b1       = (const float*)d_in[8];
    const float* Wp2      = (const float*)d_in[9];
    const float* bp2      = (const float*)d_in[10];
    const float* Ws2      = (const float*)d_in[11];
    const float* Wn2      = (const float*)d_in[12];
    const float* b2       = (const float*)d_in[13];
    float* out = (float*)d_out;

    const int N = in_sizes[0];
    const int E = in_sizes[1];

    char* ws = (char*)d_ws;
    int* rp = (int*)ws;
    size_t off = (((size_t)(N + 1) * 4) + 255) & ~(size_t)255;
    ushort_t* Wpk  = (ushort_t*)(ws + off);              // 6 x 128x128 bf16
    ushort_t* h0   = Wpk + 6 * 16384;
    ushort_t* bufM = h0 + (size_t)N * HD;
    ushort_t* bufA = bufM + (size_t)N * HD;
    ushort_t* h1   = bufA + (size_t)N * HD;

    const int nb_gemm = (N / 16 + 3) / 4;                // 4 waves/block, 16 rows/wave
    const int nb_seg  = (N + 7) / 8;

    k_rowptr<<<(N + 256) / 256, 256, 0, stream>>>(dst, E, rp, N);
    k_gather<<<(N * 32 + 255) / 256, 256, 0, stream>>>(node_ids, emb, h0, N);
    k_pack<<<6 * 64, 256, 0, stream>>>(Wp1, Ws1, Wn1, Wp2, Ws2, Wn2, Wpk);

    const ushort_t* Wp1k = Wpk;
    const ushort_t* Ws1k = Wpk + 16384;
    const ushort_t* Wn1k = Wpk + 2 * 16384;
    const ushort_t* Wp2k = Wpk + 3 * 16384;
    const ushort_t* Ws2k = Wpk + 4 * 16384;
    const ushort_t* Wn2k = Wpk + 5 * 16384;

    // layer 1
    k_pool_mfma<<<nb_gemm, 256, 0, stream>>>(h0, Wp1k, bp1, bufM, N);
    k_segmax<<<nb_seg, 256, 0, stream>>>(bufM, src, rp, bufA, N);
    k_dual_mfma<false><<<nb_gemm, 256, 0, stream>>>(h0, bufA, Ws1k, Wn1k, b1, h1, N);

    // layer 2 -> fp32 out
    k_pool_mfma<<<nb_gemm, 256, 0, stream>>>(h1, Wp2k, bp2, bufM, N);
    k_segmax<<<nb_seg, 256, 0, stream>>>(bufM, src, rp, bufA, N);
    k_dual_mfma<true><<<nb_gemm, 256, 0, stream>>>(h1, bufA, Ws2k, Wn2k, b2, out, N);
}

// Round 3
// 245.902 us; speedup vs baseline: 1.8080x; 1.0195x over previous
//
#include <hip/hip_runtime.h>

#define HD 128

typedef __attribute__((ext_vector_type(8))) short short8;   // 8 bf16 in 4 VGPRs
typedef __attribute__((ext_vector_type(4))) float floatx4;  // MFMA accumulator

typedef unsigned short ushort_t;
typedef unsigned int uint_t;

// ---------------------------------------------------------------- helpers ----
__device__ __forceinline__ ushort_t f2b(float f) {          // fp32 -> bf16 RNE
    union { float f; uint_t u; } v; v.f = f;
    uint_t r = v.u + 0x7fff + ((v.u >> 16) & 1);
    return (ushort_t)(r >> 16);
}
__device__ __forceinline__ float b_lo(uint_t p) {
    union { uint_t u; float f; } v; v.u = p << 16; return v.f;
}
__device__ __forceinline__ float b_hi(uint_t p) {
    union { uint_t u; float f; } v; v.u = p & 0xffff0000u; return v.f;
}
__device__ __forceinline__ uint_t packb(float a, float b) { // both bf16-exact
    union { float f; uint_t u; } x, y; x.f = a; y.f = b;
    return (x.u >> 16) | (y.u & 0xffff0000u);
}

// ------------------------------------------------------------------ prep -----
// One fused dispatch: [0,nbG) gather, [nbG,nbG+nbR) rowptr, rest W-pack.
__global__ __launch_bounds__(256) void k_prep(const int* __restrict__ dst, int E,
                                              int* __restrict__ rp, int N,
                                              const int* __restrict__ ids,
                                              const float* __restrict__ emb,
                                              ushort_t* __restrict__ h0,
                                              const float* W0, const float* W1,
                                              const float* W2, const float* W3,
                                              const float* W4, const float* W5,
                                              ushort_t* __restrict__ Wpk,
                                              int nbG, int nbR) {
    int b = blockIdx.x;
    if (b < nbG) {
        // gather: h0[row][:] = bf16(emb[ids[row]][:]); 32 lanes/row, float4 each
        int idx = b * 256 + threadIdx.x;
        int row = idx >> 5;
        if (row >= N) return;
        int c = (idx & 31) * 4;
        float4 v = *(const float4*)&emb[(size_t)ids[row] * HD + c];
        uint2 o;
        o.x = (uint_t)f2b(v.x) | ((uint_t)f2b(v.y) << 16);
        o.y = (uint_t)f2b(v.z) | ((uint_t)f2b(v.w) << 16);
        *(uint2*)&h0[(size_t)row * HD + c] = o;
    } else if (b < nbG + nbR) {
        // rowptr: rp[i] = lower_bound(dst, i); dst sorted
        int i = (b - nbG) * 256 + threadIdx.x;
        if (i > N) return;
        int lo = 0, hi = E;
        while (lo < hi) {
            int mid = (lo + hi) >> 1;
            if (dst[mid] < i) lo = mid + 1; else hi = mid;
        }
        rp[i] = lo;
    } else {
        // W pack into B-fragment order for mfma_f32_16x16x32_bf16:
        // Wpk[t*2048 + s*512 + l*8 + j] = bf16(W[(s*32+(l>>4)*8+j)*128 + t*16+(l&15)])
        int bb = b - nbG - nbR;
        const float* Ws[6] = {W0, W1, W2, W3, W4, W5};
        int mat = bb >> 6;
        int o = ((bb & 63) << 8) + threadIdx.x;
        int j = o & 7, l = (o >> 3) & 63, s = (o >> 9) & 3, t = o >> 11;
        int k = s * 32 + ((l >> 4) & 3) * 8 + j;
        int n = t * 16 + (l & 15);
        Wpk[(size_t)mat * 16384 + o] = f2b(Ws[mat][k * HD + n]);
    }
}

// ---------------------------------------------------------- MFMA GEMM pool ---
// m = relu(h @ W + b); 1 wave = 32 rows x 128 cols; B-frags reused across 2 row-sets.
__global__ __launch_bounds__(256) void k_pool_mfma(const ushort_t* __restrict__ h,
                                                   const ushort_t* __restrict__ Wpk,
                                                   const float* __restrict__ bias,
                                                   ushort_t* __restrict__ m, int N) {
    int wave = blockIdx.x * 4 + (threadIdx.x >> 6);
    int row0 = wave * 32;
    if (row0 >= N) return;
    int l = threadIdx.x & 63;
    int ar0 = row0 + (l & 15); if (ar0 >= N) ar0 = N - 1;
    int ar1 = ar0 + 16;        if (ar1 >= N) ar1 = N - 1;
    int ac = (l >> 4) * 8;
    short8 a0[4], a1[4];
#pragma unroll
    for (int s = 0; s < 4; ++s) {
        a0[s] = *(const short8*)&h[(size_t)ar0 * HD + s * 32 + ac];
        a1[s] = *(const short8*)&h[(size_t)ar1 * HD + s * 32 + ac];
    }
    int rb = row0 + (l >> 4) * 4;
#pragma unroll
    for (int t = 0; t < 8; ++t) {
        floatx4 acc0 = {0.f, 0.f, 0.f, 0.f};
        floatx4 acc1 = {0.f, 0.f, 0.f, 0.f};
#pragma unroll
        for (int s = 0; s < 4; ++s) {
            short8 b = *(const short8*)&Wpk[(t * 4 + s) * 512 + l * 8];
            acc0 = __builtin_amdgcn_mfma_f32_16x16x32_bf16(a0[s], b, acc0, 0, 0, 0);
            acc1 = __builtin_amdgcn_mfma_f32_16x16x32_bf16(a1[s], b, acc1, 0, 0, 0);
        }
        int col = t * 16 + (l & 15);
        float bv = bias[col];
#pragma unroll
        for (int r = 0; r < 4; ++r) {
            int g0 = rb + r, g1 = rb + 16 + r;
            if (g0 < N) m[(size_t)g0 * HD + col] = f2b(fmaxf(acc0[r] + bv, 0.f));
            if (g1 < N) m[(size_t)g1 * HD + col] = f2b(fmaxf(acc1[r] + bv, 0.f));
        }
    }
}

// ---------------------------------------------------------- MFMA GEMM dual ---
// out = h @ Wself + agg @ Wneigh + b; 32 rows/wave; F32OUT selects output dtype.
template <bool F32OUT>
__global__ __launch_bounds__(256) void k_dual_mfma(const ushort_t* __restrict__ h,
                                                   const ushort_t* __restrict__ agg,
                                                   const ushort_t* __restrict__ WsPk,
                                                   const ushort_t* __restrict__ WnPk,
                                                   const float* __restrict__ bias,
                                                   void* __restrict__ outp, int N) {
    int wave = blockIdx.x * 4 + (threadIdx.x >> 6);
    int row0 = wave * 32;
    if (row0 >= N) return;
    int l = threadIdx.x & 63;
    int ar0 = row0 + (l & 15); if (ar0 >= N) ar0 = N - 1;
    int ar1 = ar0 + 16;        if (ar1 >= N) ar1 = N - 1;
    int ac = (l >> 4) * 8;
    short8 ah0[4], ah1[4], ag0[4], ag1[4];
#pragma unroll
    for (int s = 0; s < 4; ++s) {
        ah0[s] = *(const short8*)&h[(size_t)ar0 * HD + s * 32 + ac];
        ah1[s] = *(const short8*)&h[(size_t)ar1 * HD + s * 32 + ac];
        ag0[s] = *(const short8*)&agg[(size_t)ar0 * HD + s * 32 + ac];
        ag1[s] = *(const short8*)&agg[(size_t)ar1 * HD + s * 32 + ac];
    }
    int rb = row0 + (l >> 4) * 4;
#pragma unroll
    for (int t = 0; t < 8; ++t) {
        floatx4 acc0 = {0.f, 0.f, 0.f, 0.f};
        floatx4 acc1 = {0.f, 0.f, 0.f, 0.f};
#pragma unroll
        for (int s = 0; s < 4; ++s) {
            short8 bs = *(const short8*)&WsPk[(t * 4 + s) * 512 + l * 8];
            acc0 = __builtin_amdgcn_mfma_f32_16x16x32_bf16(ah0[s], bs, acc0, 0, 0, 0);
            acc1 = __builtin_amdgcn_mfma_f32_16x16x32_bf16(ah1[s], bs, acc1, 0, 0, 0);
        }
#pragma unroll
        for (int s = 0; s < 4; ++s) {
            short8 bn = *(const short8*)&WnPk[(t * 4 + s) * 512 + l * 8];
            acc0 = __builtin_amdgcn_mfma_f32_16x16x32_bf16(ag0[s], bn, acc0, 0, 0, 0);
            acc1 = __builtin_amdgcn_mfma_f32_16x16x32_bf16(ag1[s], bn, acc1, 0, 0, 0);
        }
        int col = t * 16 + (l & 15);
        float bv = bias[col];
#pragma unroll
        for (int r = 0; r < 4; ++r) {
            int g0 = rb + r, g1 = rb + 16 + r;
            float v0 = acc0[r] + bv, v1 = acc1[r] + bv;
            if (F32OUT) {
                if (g0 < N) ((float*)outp)[(size_t)g0 * HD + col] = v0;
                if (g1 < N) ((float*)outp)[(size_t)g1 * HD + col] = v1;
            } else {
                if (g0 < N) ((ushort_t*)outp)[(size_t)g0 * HD + col] = f2b(v0);
                if (g1 < N) ((ushort_t*)outp)[(size_t)g1 * HD + col] = f2b(v1);
            }
        }
    }
}

// ---------------------------------------------------------------- segmax -----
// agg[n][:] = max(0, max_{e in [rp[n],rp[n+1])} m[src[e]][:])  bf16 rows.
// 8 nodes/block, 32 lanes/node, 8B/lane; 4-edge unroll for memory-level parallelism.
__global__ __launch_bounds__(256) void k_segmax(const ushort_t* __restrict__ m,
                                                const int* __restrict__ src,
                                                const int* __restrict__ rp,
                                                ushort_t* __restrict__ agg, int N) {
    int node = blockIdx.x * 8 + (threadIdx.x >> 5);
    if (node >= N) return;
    int lane = threadIdx.x & 31;
    int beg = rp[node], end = rp[node + 1];
    float a0 = 0.f, a1 = 0.f, a2 = 0.f, a3 = 0.f;   // acc set A
    float c0 = 0.f, c1 = 0.f, c2 = 0.f, c3 = 0.f;   // acc set B
    int e = beg;
    int e4 = beg + ((end - beg) & ~3);
    for (; e < e4; e += 4) {
        int s0 = src[e], s1 = src[e + 1], s2 = src[e + 2], s3 = src[e + 3];
        uint2 p0 = *(const uint2*)&m[(size_t)s0 * HD + lane * 4];
        uint2 p1 = *(const uint2*)&m[(size_t)s1 * HD + lane * 4];
        uint2 p2 = *(const uint2*)&m[(size_t)s2 * HD + lane * 4];
        uint2 p3 = *(const uint2*)&m[(size_t)s3 * HD + lane * 4];
        a0 = fmaxf(a0, b_lo(p0.x)); a1 = fmaxf(a1, b_hi(p0.x));
        a2 = fmaxf(a2, b_lo(p0.y)); a3 = fmaxf(a3, b_hi(p0.y));
        c0 = fmaxf(c0, b_lo(p1.x)); c1 = fmaxf(c1, b_hi(p1.x));
        c2 = fmaxf(c2, b_lo(p1.y)); c3 = fmaxf(c3, b_hi(p1.y));
        a0 = fmaxf(a0, b_lo(p2.x)); a1 = fmaxf(a1, b_hi(p2.x));
        a2 = fmaxf(a2, b_lo(p2.y)); a3 = fmaxf(a3, b_hi(p2.y));
        c0 = fmaxf(c0, b_lo(p3.x)); c1 = fmaxf(c1, b_hi(p3.x));
        c2 = fmaxf(c2, b_lo(p3.y)); c3 = fmaxf(c3, b_hi(p3.y));
    }
    for (; e < end; ++e) {
        uint2 p = *(const uint2*)&m[(size_t)src[e] * HD + lane * 4];
        a0 = fmaxf(a0, b_lo(p.x)); a1 = fmaxf(a1, b_hi(p.x));
        a2 = fmaxf(a2, b_lo(p.y)); a3 = fmaxf(a3, b_hi(p.y));
    }
    a0 = fmaxf(a0, c0); a1 = fmaxf(a1, c1); a2 = fmaxf(a2, c2); a3 = fmaxf(a3, c3);
    uint2 o; o.x = packb(a0, a1); o.y = packb(a2, a3);
    *(uint2*)&agg[(size_t)node * HD + lane * 4] = o;
}

// ---------------------------------------------------------------- launch -----
extern "C" void kernel_launch(void* const* d_in, const int* in_sizes, int n_in,
                              void* d_out, int out_size, void* d_ws, size_t ws_size,
                              hipStream_t stream) {
    const int*   node_ids = (const int*)d_in[0];
    const int*   src      = (const int*)d_in[1];
    const int*   dst      = (const int*)d_in[2];
    const float* emb      = (const float*)d_in[3];
    const float* Wp1      = (const float*)d_in[4];
    const float* bp1      = (const float*)d_in[5];
    const float* Ws1      = (const float*)d_in[6];
    const float* Wn1      = (const float*)d_in[7];
    const float* b1       = (const float*)d_in[8];
    const float* Wp2      = (const float*)d_in[9];
    const float* bp2      = (const float*)d_in[10];
    const float* Ws2      = (const float*)d_in[11];
    const float* Wn2      = (const float*)d_in[12];
    const float* b2       = (const float*)d_in[13];
    float* out = (float*)d_out;

    const int N = in_sizes[0];
    const int E = in_sizes[1];

    char* ws = (char*)d_ws;
    int* rp = (int*)ws;
    size_t off = (((size_t)(N + 1) * 4) + 255) & ~(size_t)255;
    ushort_t* Wpk  = (ushort_t*)(ws + off);              // 6 x 128x128 bf16
    ushort_t* h0   = Wpk + 6 * 16384;
    ushort_t* bufM = h0 + (size_t)N * HD;
    ushort_t* bufA = bufM + (size_t)N * HD;
    ushort_t* h1   = bufA + (size_t)N * HD;

    const int nbG = (N * 32 + 255) / 256;                // gather blocks
    const int nbR = (N + 1 + 255) / 256;                 // rowptr blocks
    const int nbP = 6 * 64;                              // pack blocks
    const int nb_gemm = (N + 127) / 128;                 // 4 waves x 32 rows
    const int nb_seg  = (N + 7) / 8;

    k_prep<<<nbG + nbR + nbP, 256, 0, stream>>>(dst, E, rp, N, node_ids, emb, h0,
                                                Wp1, Ws1, Wn1, Wp2, Ws2, Wn2, Wpk,
                                                nbG, nbR);

    const ushort_t* Wp1k = Wpk;
    const ushort_t* Ws1k = Wpk + 16384;
    const ushort_t* Wn1k = Wpk + 2 * 16384;
    const ushort_t* Wp2k = Wpk + 3 * 16384;
    const ushort_t* Ws2k = Wpk + 4 * 16384;
    const ushort_t* Wn2k = Wpk + 5 * 16384;

    // layer 1
    k_pool_mfma<<<nb_gemm, 256, 0, stream>>>(h0, Wp1k, bp1, bufM, N);
    k_segmax<<<nb_seg, 256, 0, stream>>>(bufM, src, rp, bufA, N);
    k_dual_mfma<false><<<nb_gemm, 256, 0, stream>>>(h0, bufA, Ws1k, Wn1k, b1, h1, N);

    // layer 2 -> fp32 out
    k_pool_mfma<<<nb_gemm, 256, 0, stream>>>(h1, Wp2k, bp2, bufM, N);
    k_segmax<<<nb_seg, 256, 0, stream>>>(bufM, src, rp, bufA, N);
    k_dual_mfma<true><<<nb_gemm, 256, 0, stream>>>(h1, bufA, Ws2k, Wn2k, b2, out, N);
}

// Round 5
// 245.843 us; speedup vs baseline: 1.8084x; 1.0002x over previous
//
#include <hip/hip_runtime.h>

#define HD 128
#define LSTR 136   // LDS row stride (ushorts): 272B rows spread banks, keep 16B align

typedef __attribute__((ext_vector_type(8))) short short8;   // 8 bf16
typedef __attribute__((ext_vector_type(4))) float floatx4;  // MFMA accumulator

typedef unsigned short ushort_t;
typedef unsigned int uint_t;

// ---------------------------------------------------------------- helpers ----
__device__ __forceinline__ ushort_t f2b(float f) {          // fp32 -> bf16 RNE
    union { float f; uint_t u; } v; v.f = f;
    uint_t r = v.u + 0x7fff + ((v.u >> 16) & 1);
    return (ushort_t)(r >> 16);
}
__device__ __forceinline__ float b_lo(uint_t p) {
    union { uint_t u; float f; } v; v.u = p << 16; return v.f;
}
__device__ __forceinline__ float b_hi(uint_t p) {
    union { uint_t u; float f; } v; v.u = p & 0xffff0000u; return v.f;
}
__device__ __forceinline__ uint_t packb(float a, float b) { // both bf16-exact
    union { float f; uint_t u; } x, y; x.f = a; y.f = b;
    return (x.u >> 16) | (y.u & 0xffff0000u);
}
__device__ __forceinline__ short8 cvt8(const float* __restrict__ p) {
    float4 u = *(const float4*)p, v = *(const float4*)(p + 4);
    short8 r;
    r[0] = (short)f2b(u.x); r[1] = (short)f2b(u.y); r[2] = (short)f2b(u.z); r[3] = (short)f2b(u.w);
    r[4] = (short)f2b(v.x); r[5] = (short)f2b(v.y); r[6] = (short)f2b(v.z); r[7] = (short)f2b(v.w);
    return r;
}

// ------------------------------------------------------------------ prep -----
// [0,nbR): rowptr (rp[i] = lower_bound(dst,i)); rest: W-pack to B-frag order.
__global__ __launch_bounds__(256) void k_prep(const int* __restrict__ dst, int E,
                                              int* __restrict__ rp, int N,
                                              const float* W0, const float* W1,
                                              const float* W2, const float* W3,
                                              const float* W4, const float* W5,
                                              ushort_t* __restrict__ Wpk, int nbR) {
    int b = blockIdx.x;
    if (b < nbR) {
        int i = b * 256 + threadIdx.x;
        if (i > N) return;
        int lo = 0, hi = E;
        while (lo < hi) {
            int mid = (lo + hi) >> 1;
            if (dst[mid] < i) lo = mid + 1; else hi = mid;
        }
        rp[i] = lo;
    } else {
        // Wpk[t*2048+s*512+l*8+j] = bf16(W[(s*32+(l>>4)*8+j)*128 + t*16+(l&15)])
        int bb = b - nbR;
        const float* Ws[6] = {W0, W1, W2, W3, W4, W5};
        int mat = bb >> 6;
        int o = ((bb & 63) << 8) + threadIdx.x;
        int j = o & 7, l = (o >> 3) & 63, s = (o >> 9) & 3, t = o >> 11;
        int k = s * 32 + ((l >> 4) & 3) * 8 + j;
        int n = t * 16 + (l & 15);
        Wpk[(size_t)mat * 16384 + o] = f2b(Ws[mat][k * HD + n]);
    }
}

// ------------------------------------------------------ gather + pool GEMM ---
// h0 = bf16(emb[ids]);  m = relu(h0 @ Wpk + bias).  1 wave = 32 rows.
__global__ __launch_bounds__(256) void k_gather_pool(const int* __restrict__ ids,
                                                     const float* __restrict__ emb,
                                                     const ushort_t* __restrict__ Wpk,
                                                     const float* __restrict__ bias,
                                                     ushort_t* __restrict__ h0,
                                                     ushort_t* __restrict__ m, int N) {
    int wave = blockIdx.x * 4 + (threadIdx.x >> 6);
    int row0 = wave * 32;
    if (row0 >= N) return;
    int l = threadIdx.x & 63;
    int ar0 = row0 + (l & 15); if (ar0 >= N) ar0 = N - 1;
    int ar1 = ar0 + 16;        if (ar1 >= N) ar1 = N - 1;
    int ac = (l >> 4) * 8;
    int id0 = ids[ar0], id1 = ids[ar1];
    short8 a0[4], a1[4];
#pragma unroll
    for (int s = 0; s < 4; ++s) {
        a0[s] = cvt8(&emb[(size_t)id0 * HD + s * 32 + ac]);
        a1[s] = cvt8(&emb[(size_t)id1 * HD + s * 32 + ac]);
        *(short8*)&h0[(size_t)ar0 * HD + s * 32 + ac] = a0[s];
        *(short8*)&h0[(size_t)ar1 * HD + s * 32 + ac] = a1[s];
    }
    int rb = row0 + (l >> 4) * 4;
#pragma unroll
    for (int t = 0; t < 8; ++t) {
        floatx4 acc0 = {0.f, 0.f, 0.f, 0.f};
        floatx4 acc1 = {0.f, 0.f, 0.f, 0.f};
#pragma unroll
        for (int s = 0; s < 4; ++s) {
            short8 b = *(const short8*)&Wpk[(t * 4 + s) * 512 + l * 8];
            acc0 = __builtin_amdgcn_mfma_f32_16x16x32_bf16(a0[s], b, acc0, 0, 0, 0);
            acc1 = __builtin_amdgcn_mfma_f32_16x16x32_bf16(a1[s], b, acc1, 0, 0, 0);
        }
        int col = t * 16 + (l & 15);
        float bv = bias[col];
#pragma unroll
        for (int r = 0; r < 4; ++r) {
            int g0 = rb + r, g1 = rb + 16 + r;
            if (g0 < N) m[(size_t)g0 * HD + col] = f2b(fmaxf(acc0[r] + bv, 0.f));
            if (g1 < N) m[(size_t)g1 * HD + col] = f2b(fmaxf(acc1[r] + bv, 0.f));
        }
    }
}

// ---------------------------------------------------------------- segmax -----
// agg[n][:] = max(0, max_{e in [rp[n],rp[n+1])} m[src[e]][:]); 8-deep unroll.
__global__ __launch_bounds__(256) void k_segmax(const ushort_t* __restrict__ m,
                                                const int* __restrict__ src,
                                                const int* __restrict__ rp,
                                                ushort_t* __restrict__ agg, int N) {
    int node = blockIdx.x * 8 + (threadIdx.x >> 5);
    if (node >= N) return;
    int lane = threadIdx.x & 31;
    int beg = rp[node], end = rp[node + 1];
    float a0 = 0.f, a1 = 0.f, a2 = 0.f, a3 = 0.f;
    float c0 = 0.f, c1 = 0.f, c2 = 0.f, c3 = 0.f;
    int e = beg;
    int e8 = beg + ((end - beg) & ~7);
    for (; e < e8; e += 8) {
        uint2 p0 = *(const uint2*)&m[(size_t)src[e + 0] * HD + lane * 4];
        uint2 p1 = *(const uint2*)&m[(size_t)src[e + 1] * HD + lane * 4];
        uint2 p2 = *(const uint2*)&m[(size_t)src[e + 2] * HD + lane * 4];
        uint2 p3 = *(const uint2*)&m[(size_t)src[e + 3] * HD + lane * 4];
        uint2 p4 = *(const uint2*)&m[(size_t)src[e + 4] * HD + lane * 4];
        uint2 p5 = *(const uint2*)&m[(size_t)src[e + 5] * HD + lane * 4];
        uint2 p6 = *(const uint2*)&m[(size_t)src[e + 6] * HD + lane * 4];
        uint2 p7 = *(const uint2*)&m[(size_t)src[e + 7] * HD + lane * 4];
        a0 = fmaxf(a0, b_lo(p0.x)); a1 = fmaxf(a1, b_hi(p0.x));
        a2 = fmaxf(a2, b_lo(p0.y)); a3 = fmaxf(a3, b_hi(p0.y));
        c0 = fmaxf(c0, b_lo(p1.x)); c1 = fmaxf(c1, b_hi(p1.x));
        c2 = fmaxf(c2, b_lo(p1.y)); c3 = fmaxf(c3, b_hi(p1.y));
        a0 = fmaxf(a0, b_lo(p2.x)); a1 = fmaxf(a1, b_hi(p2.x));
        a2 = fmaxf(a2, b_lo(p2.y)); a3 = fmaxf(a3, b_hi(p2.y));
        c0 = fmaxf(c0, b_lo(p3.x)); c1 = fmaxf(c1, b_hi(p3.x));
        c2 = fmaxf(c2, b_lo(p3.y)); c3 = fmaxf(c3, b_hi(p3.y));
        a0 = fmaxf(a0, b_lo(p4.x)); a1 = fmaxf(a1, b_hi(p4.x));
        a2 = fmaxf(a2, b_lo(p4.y)); a3 = fmaxf(a3, b_hi(p4.y));
        c0 = fmaxf(c0, b_lo(p5.x)); c1 = fmaxf(c1, b_hi(p5.x));
        c2 = fmaxf(c2, b_lo(p5.y)); c3 = fmaxf(c3, b_hi(p5.y));
        a0 = fmaxf(a0, b_lo(p6.x)); a1 = fmaxf(a1, b_hi(p6.x));
        a2 = fmaxf(a2, b_lo(p6.y)); a3 = fmaxf(a3, b_hi(p6.y));
        c0 = fmaxf(c0, b_lo(p7.x)); c1 = fmaxf(c1, b_hi(p7.x));
        c2 = fmaxf(c2, b_lo(p7.y)); c3 = fmaxf(c3, b_hi(p7.y));
    }
    for (; e < end; ++e) {
        uint2 p = *(const uint2*)&m[(size_t)src[e] * HD + lane * 4];
        a0 = fmaxf(a0, b_lo(p.x)); a1 = fmaxf(a1, b_hi(p.x));
        a2 = fmaxf(a2, b_lo(p.y)); a3 = fmaxf(a3, b_hi(p.y));
    }
    a0 = fmaxf(a0, c0); a1 = fmaxf(a1, c1); a2 = fmaxf(a2, c2); a3 = fmaxf(a3, c3);
    uint2 o; o.x = packb(a0, a1); o.y = packb(a2, a3);
    *(uint2*)&agg[(size_t)node * HD + lane * 4] = o;
}

// --------------------------------------------- dual GEMM 1 + pool GEMM 2 ----
// h1 = h0@Ws + agg@Wn + b1 (regs -> LDS transpose -> wide store);
// m2 = relu(h1 @ Wp2 + bp2).
__global__ __launch_bounds__(256) void k_dual_pool(const ushort_t* __restrict__ h,
                                                   const ushort_t* __restrict__ agg,
                                                   const ushort_t* __restrict__ WsPk,
                                                   const ushort_t* __restrict__ WnPk,
                                                   const float* __restrict__ b1,
                                                   const ushort_t* __restrict__ WpPk,
                                                   const float* __restrict__ bp,
                                                   ushort_t* __restrict__ h1,
                                                   ushort_t* __restrict__ m2, int N) {
    __shared__ ushort_t ls[4 * 32 * LSTR];
    const int tid = threadIdx.x;
    const int widx = tid >> 6;
    const int l = tid & 63;
    const int row0 = (blockIdx.x * 4 + widx) * 32;
    const bool active = row0 < N;
    ushort_t* lt = &ls[widx * 32 * LSTR];
    const int ac = (l >> 4) * 8;
    const int lr = (l >> 4) * 4;

    if (active) {
        int ar0 = row0 + (l & 15); if (ar0 >= N) ar0 = N - 1;
        int ar1 = ar0 + 16;        if (ar1 >= N) ar1 = N - 1;
        short8 ah0[4], ah1[4], ag0[4], ag1[4];
#pragma unroll
        for (int s = 0; s < 4; ++s) {
            ah0[s] = *(const short8*)&h[(size_t)ar0 * HD + s * 32 + ac];
            ah1[s] = *(const short8*)&h[(size_t)ar1 * HD + s * 32 + ac];
            ag0[s] = *(const short8*)&agg[(size_t)ar0 * HD + s * 32 + ac];
            ag1[s] = *(const short8*)&agg[(size_t)ar1 * HD + s * 32 + ac];
        }
#pragma unroll
        for (int t = 0; t < 8; ++t) {
            floatx4 acc0 = {0.f, 0.f, 0.f, 0.f};
            floatx4 acc1 = {0.f, 0.f, 0.f, 0.f};
#pragma unroll
            for (int s = 0; s < 4; ++s) {
                short8 bs = *(const short8*)&WsPk[(t * 4 + s) * 512 + l * 8];
                acc0 = __builtin_amdgcn_mfma_f32_16x16x32_bf16(ah0[s], bs, acc0, 0, 0, 0);
                acc1 = __builtin_amdgcn_mfma_f32_16x16x32_bf16(ah1[s], bs, acc1, 0, 0, 0);
            }
#pragma unroll
            for (int s = 0; s < 4; ++s) {
                short8 bn = *(const short8*)&WnPk[(t * 4 + s) * 512 + l * 8];
                acc0 = __builtin_amdgcn_mfma_f32_16x16x32_bf16(ag0[s], bn, acc0, 0, 0, 0);
                acc1 = __builtin_amdgcn_mfma_f32_16x16x32_bf16(ag1[s], bn, acc1, 0, 0, 0);
            }
            int col = t * 16 + (l & 15);
            float bv = b1[col];
#pragma unroll
            for (int r = 0; r < 4; ++r) {
                lt[(lr + r) * LSTR + col]      = f2b(acc0[r] + bv);
                lt[(lr + 16 + r) * LSTR + col] = f2b(acc1[r] + bv);
            }
        }
    }
    __syncthreads();
    if (!active) return;

    // wide h1 store: 32x128 bf16 tile = 512 chunks of 16B; 64 lanes x 8 iters
#pragma unroll
    for (int i = 0; i < 8; ++i) {
        int c = l + i * 64;               // 0..511
        int row = c >> 4, cc = (c & 15) * 8;
        int gr = row0 + row;
        if (gr < N)
            *(short8*)&h1[(size_t)gr * HD + cc] = *(const short8*)&lt[row * LSTR + cc];
    }

    // pool2: A-frags straight from the LDS tile
    short8 pa0[4], pa1[4];
#pragma unroll
    for (int s = 0; s < 4; ++s) {
        pa0[s] = *(const short8*)&lt[(l & 15) * LSTR + s * 32 + ac];
        pa1[s] = *(const short8*)&lt[((l & 15) + 16) * LSTR + s * 32 + ac];
    }
    int rb = row0 + lr;
#pragma unroll
    for (int t = 0; t < 8; ++t) {
        floatx4 acc0 = {0.f, 0.f, 0.f, 0.f};
        floatx4 acc1 = {0.f, 0.f, 0.f, 0.f};
#pragma unroll
        for (int s = 0; s < 4; ++s) {
            short8 b = *(const short8*)&WpPk[(t * 4 + s) * 512 + l * 8];
            acc0 = __builtin_amdgcn_mfma_f32_16x16x32_bf16(pa0[s], b, acc0, 0, 0, 0);
            acc1 = __builtin_amdgcn_mfma_f32_16x16x32_bf16(pa1[s], b, acc1, 0, 0, 0);
        }
        int col = t * 16 + (l & 15);
        float bv = bp[col];
#pragma unroll
        for (int r = 0; r < 4; ++r) {
            int g0 = rb + r, g1 = rb + 16 + r;
            if (g0 < N) m2[(size_t)g0 * HD + col] = f2b(fmaxf(acc0[r] + bv, 0.f));
            if (g1 < N) m2[(size_t)g1 * HD + col] = f2b(fmaxf(acc1[r] + bv, 0.f));
        }
    }
}

// --------------------------------------------------------- final dual GEMM ---
// out(fp32) = h @ Wself + agg @ Wneigh + b
__global__ __launch_bounds__(256) void k_dual_f32(const ushort_t* __restrict__ h,
                                                  const ushort_t* __restrict__ agg,
                                                  const ushort_t* __restrict__ WsPk,
                                                  const ushort_t* __restrict__ WnPk,
                                                  const float* __restrict__ bias,
                                                  float* __restrict__ out, int N) {
    int wave = blockIdx.x * 4 + (threadIdx.x >> 6);
    int row0 = wave * 32;
    if (row0 >= N) return;
    int l = threadIdx.x & 63;
    int ar0 = row0 + (l & 15); if (ar0 >= N) ar0 = N - 1;
    int ar1 = ar0 + 16;        if (ar1 >= N) ar1 = N - 1;
    int ac = (l >> 4) * 8;
    short8 ah0[4], ah1[4], ag0[4], ag1[4];
#pragma unroll
    for (int s = 0; s < 4; ++s) {
        ah0[s] = *(const short8*)&h[(size_t)ar0 * HD + s * 32 + ac];
        ah1[s] = *(const short8*)&h[(size_t)ar1 * HD + s * 32 + ac];
        ag0[s] = *(const short8*)&agg[(size_t)ar0 * HD + s * 32 + ac];
        ag1[s] = *(const short8*)&agg[(size_t)ar1 * HD + s * 32 + ac];
    }
    int rb = row0 + (l >> 4) * 4;
#pragma unroll
    for (int t = 0; t < 8; ++t) {
        floatx4 acc0 = {0.f, 0.f, 0.f, 0.f};
        floatx4 acc1 = {0.f, 0.f, 0.f, 0.f};
#pragma unroll
        for (int s = 0; s < 4; ++s) {
            short8 bs = *(const short8*)&WsPk[(t * 4 + s) * 512 + l * 8];
            acc0 = __builtin_amdgcn_mfma_f32_16x16x32_bf16(ah0[s], bs, acc0, 0, 0, 0);
            acc1 = __builtin_amdgcn_mfma_f32_16x16x32_bf16(ah1[s], bs, acc1, 0, 0, 0);
        }
#pragma unroll
        for (int s = 0; s < 4; ++s) {
            short8 bn = *(const short8*)&WnPk[(t * 4 + s) * 512 + l * 8];
            acc0 = __builtin_amdgcn_mfma_f32_16x16x32_bf16(ag0[s], bn, acc0, 0, 0, 0);
            acc1 = __builtin_amdgcn_mfma_f32_16x16x32_bf16(ag1[s], bn, acc1, 0, 0, 0);
        }
        int col = t * 16 + (l & 15);
        float bv = bias[col];
#pragma unroll
        for (int r = 0; r < 4; ++r) {
            int g0 = rb + r, g1 = rb + 16 + r;
            if (g0 < N) out[(size_t)g0 * HD + col] = acc0[r] + bv;
            if (g1 < N) out[(size_t)g1 * HD + col] = acc1[r] + bv;
        }
    }
}

// ---------------------------------------------------------------- launch -----
extern "C" void kernel_launch(void* const* d_in, const int* in_sizes, int n_in,
                              void* d_out, int out_size, void* d_ws, size_t ws_size,
                              hipStream_t stream) {
    const int*   node_ids = (const int*)d_in[0];
    const int*   src      = (const int*)d_in[1];
    const int*   dst      = (const int*)d_in[2];
    const float* emb      = (const float*)d_in[3];
    const float* Wp1      = (const float*)d_in[4];
    const float* bp1      = (const float*)d_in[5];
    const float* Ws1      = (const float*)d_in[6];
    const float* Wn1      = (const float*)d_in[7];
    const float* b1       = (const float*)d_in[8];
    const float* Wp2      = (const float*)d_in[9];
    const float* bp2      = (const float*)d_in[10];
    const float* Ws2      = (const float*)d_in[11];
    const float* Wn2      = (const float*)d_in[12];
    const float* b2       = (const float*)d_in[13];
    float* out = (float*)d_out;

    const int N = in_sizes[0];
    const int E = in_sizes[1];

    char* ws = (char*)d_ws;
    int* rp = (int*)ws;
    size_t off = (((size_t)(N + 1) * 4) + 255) & ~(size_t)255;
    ushort_t* Wpk  = (ushort_t*)(ws + off);              // 6 x 128x128 bf16
    ushort_t* h0   = Wpk + 6 * 16384;
    ushort_t* h1   = h0 + (size_t)N * HD;
    ushort_t* bufM = h1 + (size_t)N * HD;
    ushort_t* bufA = bufM + (size_t)N * HD;

    const int nbR = (N + 1 + 255) / 256;
    const int nbP = 6 * 64;
    const int nb_gemm = (N + 127) / 128;                 // 4 waves x 32 rows
    const int nb_seg  = (N + 7) / 8;

    k_prep<<<nbR + nbP, 256, 0, stream>>>(dst, E, rp, N,
                                          Wp1, Ws1, Wn1, Wp2, Ws2, Wn2, Wpk, nbR);

    const ushort_t* Wp1k = Wpk;
    const ushort_t* Ws1k = Wpk + 16384;
    const ushort_t* Wn1k = Wpk + 2 * 16384;
    const ushort_t* Wp2k = Wpk + 3 * 16384;
    const ushort_t* Ws2k = Wpk + 4 * 16384;
    const ushort_t* Wn2k = Wpk + 5 * 16384;

    // layer 1 (gather fused into pool1)
    k_gather_pool<<<nb_gemm, 256, 0, stream>>>(node_ids, emb, Wp1k, bp1, h0, bufM, N);
    k_segmax<<<nb_seg, 256, 0, stream>>>(bufM, src, rp, bufA, N);
    // dual1 + pool2 fused
    k_dual_pool<<<nb_gemm, 256, 0, stream>>>(h0, bufA, Ws1k, Wn1k, b1,
                                             Wp2k, bp2, h1, bufM, N);
    k_segmax<<<nb_seg, 256, 0, stream>>>(bufM, src, rp, bufA, N);
    k_dual_f32<<<nb_gemm, 256, 0, stream>>>(h1, bufA, Ws2k, Wn2k, b2, out, N);
}

// Round 6
// 236.704 us; speedup vs baseline: 1.8782x; 1.0386x over previous
//
#include <hip/hip_runtime.h>

#define HD 128

typedef __attribute__((ext_vector_type(8))) short short8;   // 8 bf16
typedef __attribute__((ext_vector_type(4))) float floatx4;  // MFMA accumulator

typedef unsigned short ushort_t;
typedef unsigned int uint_t;

// ---------------------------------------------------------------- helpers ----
__device__ __forceinline__ ushort_t f2b(float f) {          // fp32 -> bf16 RNE
    union { float f; uint_t u; } v; v.f = f;
    uint_t r = v.u + 0x7fff + ((v.u >> 16) & 1);
    return (ushort_t)(r >> 16);
}
__device__ __forceinline__ float b_lo(uint_t p) {
    union { uint_t u; float f; } v; v.u = p << 16; return v.f;
}
__device__ __forceinline__ float b_hi(uint_t p) {
    union { uint_t u; float f; } v; v.u = p & 0xffff0000u; return v.f;
}
__device__ __forceinline__ uint_t packb(float a, float b) { // both bf16-exact
    union { float f; uint_t u; } x, y; x.f = a; y.f = b;
    return (x.u >> 16) | (y.u & 0xffff0000u);
}
__device__ __forceinline__ short8 cvt8(const float* __restrict__ p) {
    float4 u = *(const float4*)p, v = *(const float4*)(p + 4);
    short8 r;
    r[0] = (short)f2b(u.x); r[1] = (short)f2b(u.y); r[2] = (short)f2b(u.z); r[3] = (short)f2b(u.w);
    r[4] = (short)f2b(v.x); r[5] = (short)f2b(v.y); r[6] = (short)f2b(v.z); r[7] = (short)f2b(v.w);
    return r;
}

// ------------------------------------------------------------------ prep -----
// [0,nbR): rowptr (rp[i] = lower_bound(dst,i)); rest: W-pack to B-frag order.
__global__ __launch_bounds__(256) void k_prep(const int* __restrict__ dst, int E,
                                              int* __restrict__ rp, int N,
                                              const float* W0, const float* W1,
                                              const float* W2, const float* W3,
                                              const float* W4, const float* W5,
                                              ushort_t* __restrict__ Wpk, int nbR) {
    int b = blockIdx.x;
    if (b < nbR) {
        int i = b * 256 + threadIdx.x;
        if (i > N) return;
        int lo = 0, hi = E;
        while (lo < hi) {
            int mid = (lo + hi) >> 1;
            if (dst[mid] < i) lo = mid + 1; else hi = mid;
        }
        rp[i] = lo;
    } else {
        // Wpk[t*2048+s*512+l*8+j] = bf16(W[(s*32+(l>>4)*8+j)*128 + t*16+(l&15)])
        int bb = b - nbR;
        const float* Ws[6] = {W0, W1, W2, W3, W4, W5};
        int mat = bb >> 6;
        int o = ((bb & 63) << 8) + threadIdx.x;
        int j = o & 7, l = (o >> 3) & 63, s = (o >> 9) & 3, t = o >> 11;
        int k = s * 32 + ((l >> 4) & 3) * 8 + j;
        int n = t * 16 + (l & 15);
        Wpk[(size_t)mat * 16384 + o] = f2b(Ws[mat][k * HD + n]);
    }
}

// ---------------------------------------------------------- W -> LDS stage ---
__device__ __forceinline__ void stage_w(const ushort_t* __restrict__ g,
                                        ushort_t* l, int tid) {
#pragma unroll
    for (int i = 0; i < 8; ++i) {
        int off = i * 2048 + tid * 8;
        *(short8*)&l[off] = *(const short8*)&g[off];
    }
}

// ------------------------------------------------------ gather + pool GEMM ---
// h0 = bf16(emb[ids]);  m = relu(h0 @ Wpk + bias).  Wp staged in LDS per block.
__global__ __launch_bounds__(256) void k_gather_pool(const int* __restrict__ ids,
                                                     const float* __restrict__ emb,
                                                     const ushort_t* __restrict__ Wpk,
                                                     const float* __restrict__ bias,
                                                     ushort_t* __restrict__ h0,
                                                     ushort_t* __restrict__ m, int N) {
    __shared__ ushort_t Wl[16384];                       // 32 KB
    stage_w(Wpk, Wl, threadIdx.x);
    __syncthreads();

    int wave = blockIdx.x * 4 + (threadIdx.x >> 6);
    int row0 = wave * 32;
    if (row0 >= N) return;
    int l = threadIdx.x & 63;
    int ar0 = row0 + (l & 15); if (ar0 >= N) ar0 = N - 1;
    int ar1 = ar0 + 16;        if (ar1 >= N) ar1 = N - 1;
    int ac = (l >> 4) * 8;
    int id0 = ids[ar0], id1 = ids[ar1];
    short8 a0[4], a1[4];
#pragma unroll
    for (int s = 0; s < 4; ++s) {
        a0[s] = cvt8(&emb[(size_t)id0 * HD + s * 32 + ac]);
        a1[s] = cvt8(&emb[(size_t)id1 * HD + s * 32 + ac]);
        *(short8*)&h0[(size_t)ar0 * HD + s * 32 + ac] = a0[s];
        *(short8*)&h0[(size_t)ar1 * HD + s * 32 + ac] = a1[s];
    }
    int rb = row0 + (l >> 4) * 4;
#pragma unroll
    for (int t = 0; t < 8; ++t) {
        floatx4 acc0 = {0.f, 0.f, 0.f, 0.f};
        floatx4 acc1 = {0.f, 0.f, 0.f, 0.f};
#pragma unroll
        for (int s = 0; s < 4; ++s) {
            short8 b = *(const short8*)&Wl[(t * 4 + s) * 512 + l * 8];
            acc0 = __builtin_amdgcn_mfma_f32_16x16x32_bf16(a0[s], b, acc0, 0, 0, 0);
            acc1 = __builtin_amdgcn_mfma_f32_16x16x32_bf16(a1[s], b, acc1, 0, 0, 0);
        }
        int col = t * 16 + (l & 15);
        float bv = bias[col];
#pragma unroll
        for (int r = 0; r < 4; ++r) {
            int g0 = rb + r, g1 = rb + 16 + r;
            if (g0 < N) m[(size_t)g0 * HD + col] = f2b(fmaxf(acc0[r] + bv, 0.f));
            if (g1 < N) m[(size_t)g1 * HD + col] = f2b(fmaxf(acc1[r] + bv, 0.f));
        }
    }
}

// ----------------------------------------------------------- pool GEMM only --
__global__ __launch_bounds__(256) void k_pool(const ushort_t* __restrict__ h,
                                              const ushort_t* __restrict__ Wpk,
                                              const float* __restrict__ bias,
                                              ushort_t* __restrict__ m, int N) {
    __shared__ ushort_t Wl[16384];
    stage_w(Wpk, Wl, threadIdx.x);
    __syncthreads();

    int wave = blockIdx.x * 4 + (threadIdx.x >> 6);
    int row0 = wave * 32;
    if (row0 >= N) return;
    int l = threadIdx.x & 63;
    int ar0 = row0 + (l & 15); if (ar0 >= N) ar0 = N - 1;
    int ar1 = ar0 + 16;        if (ar1 >= N) ar1 = N - 1;
    int ac = (l >> 4) * 8;
    short8 a0[4], a1[4];
#pragma unroll
    for (int s = 0; s < 4; ++s) {
        a0[s] = *(const short8*)&h[(size_t)ar0 * HD + s * 32 + ac];
        a1[s] = *(const short8*)&h[(size_t)ar1 * HD + s * 32 + ac];
    }
    int rb = row0 + (l >> 4) * 4;
#pragma unroll
    for (int t = 0; t < 8; ++t) {
        floatx4 acc0 = {0.f, 0.f, 0.f, 0.f};
        floatx4 acc1 = {0.f, 0.f, 0.f, 0.f};
#pragma unroll
        for (int s = 0; s < 4; ++s) {
            short8 b = *(const short8*)&Wl[(t * 4 + s) * 512 + l * 8];
            acc0 = __builtin_amdgcn_mfma_f32_16x16x32_bf16(a0[s], b, acc0, 0, 0, 0);
            acc1 = __builtin_amdgcn_mfma_f32_16x16x32_bf16(a1[s], b, acc1, 0, 0, 0);
        }
        int col = t * 16 + (l & 15);
        float bv = bias[col];
#pragma unroll
        for (int r = 0; r < 4; ++r) {
            int g0 = rb + r, g1 = rb + 16 + r;
            if (g0 < N) m[(size_t)g0 * HD + col] = f2b(fmaxf(acc0[r] + bv, 0.f));
            if (g1 < N) m[(size_t)g1 * HD + col] = f2b(fmaxf(acc1[r] + bv, 0.f));
        }
    }
}

// ---------------------------------------------------------------- segmax -----
// One node per wave; half-waves take consecutive edges of the SAME node
// (zero divergence). agg[n][:] = max(0, max_e m[src[e]][:]).
__global__ __launch_bounds__(256) void k_segmax(const ushort_t* __restrict__ m,
                                                const int* __restrict__ src,
                                                const int* __restrict__ rp,
                                                ushort_t* __restrict__ agg, int N) {
    int node = blockIdx.x * 4 + (threadIdx.x >> 6);
    if (node >= N) return;
    int l = threadIdx.x & 63;
    int half = l >> 5;                 // 0/1: which edge of the pair
    int col4 = (l & 31) * 4;           // 4 bf16 (8 B) per lane
    int beg = rp[node], end = rp[node + 1];
    float a0 = 0.f, a1 = 0.f, a2 = 0.f, a3 = 0.f;
    float c0 = 0.f, c1 = 0.f, c2 = 0.f, c3 = 0.f;
    int e = beg;
    for (; e + 8 <= end; e += 8) {     // 8 edges, 4 loads/lane in flight
        int e0 = e + half, e1 = e + 2 + half, e2 = e + 4 + half, e3 = e + 6 + half;
        uint2 p0 = *(const uint2*)&m[(size_t)src[e0] * HD + col4];
        uint2 p1 = *(const uint2*)&m[(size_t)src[e1] * HD + col4];
        uint2 p2 = *(const uint2*)&m[(size_t)src[e2] * HD + col4];
        uint2 p3 = *(const uint2*)&m[(size_t)src[e3] * HD + col4];
        a0 = fmaxf(a0, b_lo(p0.x)); a1 = fmaxf(a1, b_hi(p0.x));
        a2 = fmaxf(a2, b_lo(p0.y)); a3 = fmaxf(a3, b_hi(p0.y));
        c0 = fmaxf(c0, b_lo(p1.x)); c1 = fmaxf(c1, b_hi(p1.x));
        c2 = fmaxf(c2, b_lo(p1.y)); c3 = fmaxf(c3, b_hi(p1.y));
        a0 = fmaxf(a0, b_lo(p2.x)); a1 = fmaxf(a1, b_hi(p2.x));
        a2 = fmaxf(a2, b_lo(p2.y)); a3 = fmaxf(a3, b_hi(p2.y));
        c0 = fmaxf(c0, b_lo(p3.x)); c1 = fmaxf(c1, b_hi(p3.x));
        c2 = fmaxf(c2, b_lo(p3.y)); c3 = fmaxf(c3, b_hi(p3.y));
    }
    for (; e < end; e += 2) {          // tail: odd edge duplicated (max idempotent)
        int ee = e + half; if (ee >= end) ee = end - 1;
        uint2 p = *(const uint2*)&m[(size_t)src[ee] * HD + col4];
        a0 = fmaxf(a0, b_lo(p.x)); a1 = fmaxf(a1, b_hi(p.x));
        a2 = fmaxf(a2, b_lo(p.y)); a3 = fmaxf(a3, b_hi(p.y));
    }
    a0 = fmaxf(a0, c0); a1 = fmaxf(a1, c1); a2 = fmaxf(a2, c2); a3 = fmaxf(a3, c3);
    // merge the two half-wave accumulators (lanes l and l^32 hold same columns)
    a0 = fmaxf(a0, __shfl_xor(a0, 32));
    a1 = fmaxf(a1, __shfl_xor(a1, 32));
    a2 = fmaxf(a2, __shfl_xor(a2, 32));
    a3 = fmaxf(a3, __shfl_xor(a3, 32));
    if (half == 0) {
        uint2 o; o.x = packb(a0, a1); o.y = packb(a2, a3);
        *(uint2*)&agg[(size_t)node * HD + col4] = o;
    }
}

// ----------------------------------------------------------- dual GEMM -------
// out = h @ Wself + agg @ Wneigh + b; both W staged in LDS (64 KB).
template <bool F32OUT>
__global__ __launch_bounds__(256) void k_dual(const ushort_t* __restrict__ h,
                                              const ushort_t* __restrict__ agg,
                                              const ushort_t* __restrict__ WsPk,
                                              const ushort_t* __restrict__ WnPk,
                                              const float* __restrict__ bias,
                                              void* __restrict__ outp, int N) {
    __shared__ ushort_t Wl[32768];                       // Ws | Wn
    stage_w(WsPk, Wl, threadIdx.x);
    stage_w(WnPk, Wl + 16384, threadIdx.x);
    __syncthreads();

    int wave = blockIdx.x * 4 + (threadIdx.x >> 6);
    int row0 = wave * 32;
    if (row0 >= N) return;
    int l = threadIdx.x & 63;
    int ar0 = row0 + (l & 15); if (ar0 >= N) ar0 = N - 1;
    int ar1 = ar0 + 16;        if (ar1 >= N) ar1 = N - 1;
    int ac = (l >> 4) * 8;
    short8 ah0[4], ah1[4], ag0[4], ag1[4];
#pragma unroll
    for (int s = 0; s < 4; ++s) {
        ah0[s] = *(const short8*)&h[(size_t)ar0 * HD + s * 32 + ac];
        ah1[s] = *(const short8*)&h[(size_t)ar1 * HD + s * 32 + ac];
        ag0[s] = *(const short8*)&agg[(size_t)ar0 * HD + s * 32 + ac];
        ag1[s] = *(const short8*)&agg[(size_t)ar1 * HD + s * 32 + ac];
    }
    int rb = row0 + (l >> 4) * 4;
#pragma unroll
    for (int t = 0; t < 8; ++t) {
        floatx4 acc0 = {0.f, 0.f, 0.f, 0.f};
        floatx4 acc1 = {0.f, 0.f, 0.f, 0.f};
#pragma unroll
        for (int s = 0; s < 4; ++s) {
            short8 bs = *(const short8*)&Wl[(t * 4 + s) * 512 + l * 8];
            acc0 = __builtin_amdgcn_mfma_f32_16x16x32_bf16(ah0[s], bs, acc0, 0, 0, 0);
            acc1 = __builtin_amdgcn_mfma_f32_16x16x32_bf16(ah1[s], bs, acc1, 0, 0, 0);
        }
#pragma unroll
        for (int s = 0; s < 4; ++s) {
            short8 bn = *(const short8*)&Wl[16384 + (t * 4 + s) * 512 + l * 8];
            acc0 = __builtin_amdgcn_mfma_f32_16x16x32_bf16(ag0[s], bn, acc0, 0, 0, 0);
            acc1 = __builtin_amdgcn_mfma_f32_16x16x32_bf16(ag1[s], bn, acc1, 0, 0, 0);
        }
        int col = t * 16 + (l & 15);
        float bv = bias[col];
#pragma unroll
        for (int r = 0; r < 4; ++r) {
            int g0 = rb + r, g1 = rb + 16 + r;
            float v0 = acc0[r] + bv, v1 = acc1[r] + bv;
            if (F32OUT) {
                if (g0 < N) ((float*)outp)[(size_t)g0 * HD + col] = v0;
                if (g1 < N) ((float*)outp)[(size_t)g1 * HD + col] = v1;
            } else {
                if (g0 < N) ((ushort_t*)outp)[(size_t)g0 * HD + col] = f2b(v0);
                if (g1 < N) ((ushort_t*)outp)[(size_t)g1 * HD + col] = f2b(v1);
            }
        }
    }
}

// ---------------------------------------------------------------- launch -----
extern "C" void kernel_launch(void* const* d_in, const int* in_sizes, int n_in,
                              void* d_out, int out_size, void* d_ws, size_t ws_size,
                              hipStream_t stream) {
    const int*   node_ids = (const int*)d_in[0];
    const int*   src      = (const int*)d_in[1];
    const int*   dst      = (const int*)d_in[2];
    const float* emb      = (const float*)d_in[3];
    const float* Wp1      = (const float*)d_in[4];
    const float* bp1      = (const float*)d_in[5];
    const float* Ws1      = (const float*)d_in[6];
    const float* Wn1      = (const float*)d_in[7];
    const float* b1       = (const float*)d_in[8];
    const float* Wp2      = (const float*)d_in[9];
    const float* bp2      = (const float*)d_in[10];
    const float* Ws2      = (const float*)d_in[11];
    const float* Wn2      = (const float*)d_in[12];
    const float* b2       = (const float*)d_in[13];
    float* out = (float*)d_out;

    const int N = in_sizes[0];
    const int E = in_sizes[1];

    char* ws = (char*)d_ws;
    int* rp = (int*)ws;
    size_t off = (((size_t)(N + 1) * 4) + 255) & ~(size_t)255;
    ushort_t* Wpk  = (ushort_t*)(ws + off);              // 6 x 128x128 bf16
    ushort_t* h0   = Wpk + 6 * 16384;
    ushort_t* h1   = h0 + (size_t)N * HD;
    ushort_t* bufM = h1 + (size_t)N * HD;
    ushort_t* bufA = bufM + (size_t)N * HD;

    const int nbR = (N + 1 + 255) / 256;
    const int nbP = 6 * 64;
    const int nb_gemm = (N + 127) / 128;                 // 4 waves x 32 rows
    const int nb_seg  = (N + 3) / 4;                     // 1 node per wave

    k_prep<<<nbR + nbP, 256, 0, stream>>>(dst, E, rp, N,
                                          Wp1, Ws1, Wn1, Wp2, Ws2, Wn2, Wpk, nbR);

    const ushort_t* Wp1k = Wpk;
    const ushort_t* Ws1k = Wpk + 16384;
    const ushort_t* Wn1k = Wpk + 2 * 16384;
    const ushort_t* Wp2k = Wpk + 3 * 16384;
    const ushort_t* Ws2k = Wpk + 4 * 16384;
    const ushort_t* Wn2k = Wpk + 5 * 16384;

    // layer 1
    k_gather_pool<<<nb_gemm, 256, 0, stream>>>(node_ids, emb, Wp1k, bp1, h0, bufM, N);
    k_segmax<<<nb_seg, 256, 0, stream>>>(bufM, src, rp, bufA, N);
    k_dual<false><<<nb_gemm, 256, 0, stream>>>(h0, bufA, Ws1k, Wn1k, b1, h1, N);
    // layer 2
    k_pool<<<nb_gemm, 256, 0, stream>>>(h1, Wp2k, bp2, bufM, N);
    k_segmax<<<nb_seg, 256, 0, stream>>>(bufM, src, rp, bufA, N);
    k_dual<true><<<nb_gemm, 256, 0, stream>>>(h1, bufA, Ws2k, Wn2k, b2, out, N);
}

// Round 7
// 222.661 us; speedup vs baseline: 1.9967x; 1.0631x over previous
//
#include <hip/hip_runtime.h>

#define HD 128

typedef __attribute__((ext_vector_type(8))) short short8;   // 8 bf16
typedef __attribute__((ext_vector_type(4))) float floatx4;  // MFMA accumulator

typedef unsigned short ushort_t;
typedef unsigned int uint_t;

// ---------------------------------------------------------------- helpers ----
__device__ __forceinline__ ushort_t f2b(float f) {          // fp32 -> bf16 RNE
    union { float f; uint_t u; } v; v.f = f;
    uint_t r = v.u + 0x7fff + ((v.u >> 16) & 1);
    return (ushort_t)(r >> 16);
}
__device__ __forceinline__ float b_lo(uint_t p) {
    union { uint_t u; float f; } v; v.u = p << 16; return v.f;
}
__device__ __forceinline__ float b_hi(uint_t p) {
    union { uint_t u; float f; } v; v.u = p & 0xffff0000u; return v.f;
}
__device__ __forceinline__ uint_t packb(float a, float b) { // both bf16-exact
    union { float f; uint_t u; } x, y; x.f = a; y.f = b;
    return (x.u >> 16) | (y.u & 0xffff0000u);
}
__device__ __forceinline__ short8 cvt8(const float* __restrict__ p) {
    float4 u = *(const float4*)p, v = *(const float4*)(p + 4);
    short8 r;
    r[0] = (short)f2b(u.x); r[1] = (short)f2b(u.y); r[2] = (short)f2b(u.z); r[3] = (short)f2b(u.w);
    r[4] = (short)f2b(v.x); r[5] = (short)f2b(v.y); r[6] = (short)f2b(v.z); r[7] = (short)f2b(v.w);
    return r;
}

// ------------------------------------------------------------------ prep -----
// [0,nbR): rowptr (rp[i] = lower_bound(dst,i)); rest: W-pack to frag order.
// Frag map (identical for A- and B-operand): lane&15 -> non-K dim, quad*8+j -> K.
__global__ __launch_bounds__(256) void k_prep(const int* __restrict__ dst, int E,
                                              int* __restrict__ rp, int N,
                                              const float* W0, const float* W1,
                                              const float* W2, const float* W3,
                                              const float* W4, const float* W5,
                                              ushort_t* __restrict__ Wpk, int nbR) {
    int b = blockIdx.x;
    if (b < nbR) {
        int i = b * 256 + threadIdx.x;
        if (i > N) return;
        int lo = 0, hi = E;
        while (lo < hi) {
            int mid = (lo + hi) >> 1;
            if (dst[mid] < i) lo = mid + 1; else hi = mid;
        }
        rp[i] = lo;
    } else {
        int bb = b - nbR;
        const float* Ws[6] = {W0, W1, W2, W3, W4, W5};
        int mat = bb >> 6;
        int o = ((bb & 63) << 8) + threadIdx.x;
        int j = o & 7, l = (o >> 3) & 63, s = (o >> 9) & 3, t = o >> 11;
        int k = s * 32 + ((l >> 4) & 3) * 8 + j;
        int n = t * 16 + (l & 15);
        Wpk[(size_t)mat * 16384 + o] = f2b(Ws[mat][k * HD + n]);
    }
}

// ---------------------------------------------------------- W -> LDS stage ---
__device__ __forceinline__ void stage_w(const ushort_t* __restrict__ g,
                                        ushort_t* l, int tid) {
#pragma unroll
    for (int i = 0; i < 8; ++i) {
        int off = i * 2048 + tid * 8;
        *(short8*)&l[off] = *(const short8*)&g[off];
    }
}

// --------------------------------------------------------------- epilogues ---
// D = mfma(Wfrag, hfrag): lane&15 = h-row, quad*4+reg = output col within tile.
// -> per t, per row-set: one 8B (bf16) or 16B (fp32) store of 4 consecutive cols.
__device__ __forceinline__ void store_bf16(ushort_t* __restrict__ m, int row,
                                           int colbase, const floatx4& acc,
                                           const float4& bv, bool relu, int N) {
    if (row >= N) return;
    float v0 = acc[0] + bv.x, v1 = acc[1] + bv.y, v2 = acc[2] + bv.z, v3 = acc[3] + bv.w;
    if (relu) { v0 = fmaxf(v0, 0.f); v1 = fmaxf(v1, 0.f); v2 = fmaxf(v2, 0.f); v3 = fmaxf(v3, 0.f); }
    uint2 o; o.x = (uint_t)f2b(v0) | ((uint_t)f2b(v1) << 16);
    o.y = (uint_t)f2b(v2) | ((uint_t)f2b(v3) << 16);
    *(uint2*)&m[(size_t)row * HD + colbase] = o;
}

// ------------------------------------------------------ gather + pool GEMM ---
// h0 = bf16(emb[ids]);  m = relu(h0 @ Wp + b).  Transposed-D epilogue.
__global__ __launch_bounds__(256) void k_gather_pool(const int* __restrict__ ids,
                                                     const float* __restrict__ emb,
                                                     const ushort_t* __restrict__ Wpk,
                                                     const float* __restrict__ bias,
                                                     ushort_t* __restrict__ h0,
                                                     ushort_t* __restrict__ m, int N) {
    __shared__ ushort_t Wl[16384];
    stage_w(Wpk, Wl, threadIdx.x);
    __syncthreads();

    int wave = blockIdx.x * 4 + (threadIdx.x >> 6);
    int row0 = wave * 32;
    if (row0 >= N) return;
    int l = threadIdx.x & 63;
    int ar0 = row0 + (l & 15); if (ar0 >= N) ar0 = N - 1;
    int ar1 = ar0 + 16;        if (ar1 >= N) ar1 = N - 1;
    int ac = (l >> 4) * 8;
    int id0 = ids[ar0], id1 = ids[ar1];
    short8 a0[4], a1[4];
#pragma unroll
    for (int s = 0; s < 4; ++s) {
        a0[s] = cvt8(&emb[(size_t)id0 * HD + s * 32 + ac]);
        a1[s] = cvt8(&emb[(size_t)id1 * HD + s * 32 + ac]);
        *(short8*)&h0[(size_t)ar0 * HD + s * 32 + ac] = a0[s];
        *(short8*)&h0[(size_t)ar1 * HD + s * 32 + ac] = a1[s];
    }
    int g0 = row0 + (l & 15), g1 = g0 + 16;
    int cb0 = ((l >> 4) & 3) * 4;
#pragma unroll
    for (int t = 0; t < 8; ++t) {
        floatx4 acc0 = {0.f, 0.f, 0.f, 0.f};
        floatx4 acc1 = {0.f, 0.f, 0.f, 0.f};
#pragma unroll
        for (int s = 0; s < 4; ++s) {
            short8 w = *(const short8*)&Wl[(t * 4 + s) * 512 + l * 8];
            acc0 = __builtin_amdgcn_mfma_f32_16x16x32_bf16(w, a0[s], acc0, 0, 0, 0);
            acc1 = __builtin_amdgcn_mfma_f32_16x16x32_bf16(w, a1[s], acc1, 0, 0, 0);
        }
        int cb = t * 16 + cb0;
        float4 bv = *(const float4*)&bias[cb];
        store_bf16(m, g0, cb, acc0, bv, true, N);
        store_bf16(m, g1, cb, acc1, bv, true, N);
    }
}

// ----------------------------------------------------------- pool GEMM only --
__global__ __launch_bounds__(256) void k_pool(const ushort_t* __restrict__ h,
                                              const ushort_t* __restrict__ Wpk,
                                              const float* __restrict__ bias,
                                              ushort_t* __restrict__ m, int N) {
    __shared__ ushort_t Wl[16384];
    stage_w(Wpk, Wl, threadIdx.x);
    __syncthreads();

    int wave = blockIdx.x * 4 + (threadIdx.x >> 6);
    int row0 = wave * 32;
    if (row0 >= N) return;
    int l = threadIdx.x & 63;
    int ar0 = row0 + (l & 15); if (ar0 >= N) ar0 = N - 1;
    int ar1 = ar0 + 16;        if (ar1 >= N) ar1 = N - 1;
    int ac = (l >> 4) * 8;
    short8 a0[4], a1[4];
#pragma unroll
    for (int s = 0; s < 4; ++s) {
        a0[s] = *(const short8*)&h[(size_t)ar0 * HD + s * 32 + ac];
        a1[s] = *(const short8*)&h[(size_t)ar1 * HD + s * 32 + ac];
    }
    int g0 = row0 + (l & 15), g1 = g0 + 16;
    int cb0 = ((l >> 4) & 3) * 4;
#pragma unroll
    for (int t = 0; t < 8; ++t) {
        floatx4 acc0 = {0.f, 0.f, 0.f, 0.f};
        floatx4 acc1 = {0.f, 0.f, 0.f, 0.f};
#pragma unroll
        for (int s = 0; s < 4; ++s) {
            short8 w = *(const short8*)&Wl[(t * 4 + s) * 512 + l * 8];
            acc0 = __builtin_amdgcn_mfma_f32_16x16x32_bf16(w, a0[s], acc0, 0, 0, 0);
            acc1 = __builtin_amdgcn_mfma_f32_16x16x32_bf16(w, a1[s], acc1, 0, 0, 0);
        }
        int cb = t * 16 + cb0;
        float4 bv = *(const float4*)&bias[cb];
        store_bf16(m, g0, cb, acc0, bv, true, N);
        store_bf16(m, g1, cb, acc1, bv, true, N);
    }
}

// ---------------------------------------------------------------- segmax -----
// One node per wave; 4 edge-slots x 16 lanes x 16B (full 256B row per slot).
__global__ __launch_bounds__(256) void k_segmax(const ushort_t* __restrict__ m,
                                                const int* __restrict__ src,
                                                const int* __restrict__ rp,
                                                ushort_t* __restrict__ agg, int N) {
    int node = blockIdx.x * 4 + (threadIdx.x >> 6);
    if (node >= N) return;
    int l = threadIdx.x & 63;
    int slot = l >> 4;                 // 0..3: which edge of a 4-group
    int col8 = (l & 15) * 8;           // 8 bf16 (16 B) per lane
    int beg = rp[node], end = rp[node + 1];
    float a[8] = {0.f, 0.f, 0.f, 0.f, 0.f, 0.f, 0.f, 0.f};
    float c[8] = {0.f, 0.f, 0.f, 0.f, 0.f, 0.f, 0.f, 0.f};
    int e = beg;
    for (; e + 16 <= end; e += 16) {   // 16 edges, 4 loads/lane in flight
        uint4 p0 = *(const uint4*)&m[(size_t)src[e + slot] * HD + col8];
        uint4 p1 = *(const uint4*)&m[(size_t)src[e + 4 + slot] * HD + col8];
        uint4 p2 = *(const uint4*)&m[(size_t)src[e + 8 + slot] * HD + col8];
        uint4 p3 = *(const uint4*)&m[(size_t)src[e + 12 + slot] * HD + col8];
        a[0] = fmaxf(a[0], b_lo(p0.x)); a[1] = fmaxf(a[1], b_hi(p0.x));
        a[2] = fmaxf(a[2], b_lo(p0.y)); a[3] = fmaxf(a[3], b_hi(p0.y));
        a[4] = fmaxf(a[4], b_lo(p0.z)); a[5] = fmaxf(a[5], b_hi(p0.z));
        a[6] = fmaxf(a[6], b_lo(p0.w)); a[7] = fmaxf(a[7], b_hi(p0.w));
        c[0] = fmaxf(c[0], b_lo(p1.x)); c[1] = fmaxf(c[1], b_hi(p1.x));
        c[2] = fmaxf(c[2], b_lo(p1.y)); c[3] = fmaxf(c[3], b_hi(p1.y));
        c[4] = fmaxf(c[4], b_lo(p1.z)); c[5] = fmaxf(c[5], b_hi(p1.z));
        c[6] = fmaxf(c[6], b_lo(p1.w)); c[7] = fmaxf(c[7], b_hi(p1.w));
        a[0] = fmaxf(a[0], b_lo(p2.x)); a[1] = fmaxf(a[1], b_hi(p2.x));
        a[2] = fmaxf(a[2], b_lo(p2.y)); a[3] = fmaxf(a[3], b_hi(p2.y));
        a[4] = fmaxf(a[4], b_lo(p2.z)); a[5] = fmaxf(a[5], b_hi(p2.z));
        a[6] = fmaxf(a[6], b_lo(p2.w)); a[7] = fmaxf(a[7], b_hi(p2.w));
        c[0] = fmaxf(c[0], b_lo(p3.x)); c[1] = fmaxf(c[1], b_hi(p3.x));
        c[2] = fmaxf(c[2], b_lo(p3.y)); c[3] = fmaxf(c[3], b_hi(p3.y));
        c[4] = fmaxf(c[4], b_lo(p3.z)); c[5] = fmaxf(c[5], b_hi(p3.z));
        c[6] = fmaxf(c[6], b_lo(p3.w)); c[7] = fmaxf(c[7], b_hi(p3.w));
    }
    for (; e < end; e += 4) {          // tail: clamp (max is idempotent)
        int ee = e + slot; if (ee >= end) ee = end - 1;
        uint4 p = *(const uint4*)&m[(size_t)src[ee] * HD + col8];
        a[0] = fmaxf(a[0], b_lo(p.x)); a[1] = fmaxf(a[1], b_hi(p.x));
        a[2] = fmaxf(a[2], b_lo(p.y)); a[3] = fmaxf(a[3], b_hi(p.y));
        a[4] = fmaxf(a[4], b_lo(p.z)); a[5] = fmaxf(a[5], b_hi(p.z));
        a[6] = fmaxf(a[6], b_lo(p.w)); a[7] = fmaxf(a[7], b_hi(p.w));
    }
#pragma unroll
    for (int i = 0; i < 8; ++i) {
        a[i] = fmaxf(a[i], c[i]);
        a[i] = fmaxf(a[i], __shfl_xor(a[i], 16));
        a[i] = fmaxf(a[i], __shfl_xor(a[i], 32));
    }
    if (slot == 0) {
        uint4 o;
        o.x = packb(a[0], a[1]); o.y = packb(a[2], a[3]);
        o.z = packb(a[4], a[5]); o.w = packb(a[6], a[7]);
        *(uint4*)&agg[(size_t)node * HD + col8] = o;
    }
}

// ----------------------------------------------------------- dual GEMM -------
// out = h @ Wself + agg @ Wneigh + b; transposed-D epilogue; W in LDS.
template <bool F32OUT>
__global__ __launch_bounds__(256) void k_dual(const ushort_t* __restrict__ h,
                                              const ushort_t* __restrict__ agg,
                                              const ushort_t* __restrict__ WsPk,
                                              const ushort_t* __restrict__ WnPk,
                                              const float* __restrict__ bias,
                                              void* __restrict__ outp, int N) {
    __shared__ ushort_t Wl[32768];                       // Ws | Wn
    stage_w(WsPk, Wl, threadIdx.x);
    stage_w(WnPk, Wl + 16384, threadIdx.x);
    __syncthreads();

    int wave = blockIdx.x * 4 + (threadIdx.x >> 6);
    int row0 = wave * 32;
    if (row0 >= N) return;
    int l = threadIdx.x & 63;
    int ar0 = row0 + (l & 15); if (ar0 >= N) ar0 = N - 1;
    int ar1 = ar0 + 16;        if (ar1 >= N) ar1 = N - 1;
    int ac = (l >> 4) * 8;
    short8 ah0[4], ah1[4], ag0[4], ag1[4];
#pragma unroll
    for (int s = 0; s < 4; ++s) {
        ah0[s] = *(const short8*)&h[(size_t)ar0 * HD + s * 32 + ac];
        ah1[s] = *(const short8*)&h[(size_t)ar1 * HD + s * 32 + ac];
        ag0[s] = *(const short8*)&agg[(size_t)ar0 * HD + s * 32 + ac];
        ag1[s] = *(const short8*)&agg[(size_t)ar1 * HD + s * 32 + ac];
    }
    int g0 = row0 + (l & 15), g1 = g0 + 16;
    int cb0 = ((l >> 4) & 3) * 4;
#pragma unroll
    for (int t = 0; t < 8; ++t) {
        floatx4 acc0 = {0.f, 0.f, 0.f, 0.f};
        floatx4 acc1 = {0.f, 0.f, 0.f, 0.f};
#pragma unroll
        for (int s = 0; s < 4; ++s) {
            short8 ws = *(const short8*)&Wl[(t * 4 + s) * 512 + l * 8];
            acc0 = __builtin_amdgcn_mfma_f32_16x16x32_bf16(ws, ah0[s], acc0, 0, 0, 0);
            acc1 = __builtin_amdgcn_mfma_f32_16x16x32_bf16(ws, ah1[s], acc1, 0, 0, 0);
        }
#pragma unroll
        for (int s = 0; s < 4; ++s) {
            short8 wn = *(const short8*)&Wl[16384 + (t * 4 + s) * 512 + l * 8];
            acc0 = __builtin_amdgcn_mfma_f32_16x16x32_bf16(wn, ag0[s], acc0, 0, 0, 0);
            acc1 = __builtin_amdgcn_mfma_f32_16x16x32_bf16(wn, ag1[s], acc1, 0, 0, 0);
        }
        int cb = t * 16 + cb0;
        float4 bv = *(const float4*)&bias[cb];
        if (F32OUT) {
            float* out = (float*)outp;
            if (g0 < N) {
                float4 v = make_float4(acc0[0] + bv.x, acc0[1] + bv.y,
                                       acc0[2] + bv.z, acc0[3] + bv.w);
                *(float4*)&out[(size_t)g0 * HD + cb] = v;
            }
            if (g1 < N) {
                float4 v = make_float4(acc1[0] + bv.x, acc1[1] + bv.y,
                                       acc1[2] + bv.z, acc1[3] + bv.w);
                *(float4*)&out[(size_t)g1 * HD + cb] = v;
            }
        } else {
            ushort_t* out = (ushort_t*)outp;
            store_bf16(out, g0, cb, acc0, bv, false, N);
            store_bf16(out, g1, cb, acc1, bv, false, N);
        }
    }
}

// ---------------------------------------------------------------- launch -----
extern "C" void kernel_launch(void* const* d_in, const int* in_sizes, int n_in,
                              void* d_out, int out_size, void* d_ws, size_t ws_size,
                              hipStream_t stream) {
    const int*   node_ids = (const int*)d_in[0];
    const int*   src      = (const int*)d_in[1];
    const int*   dst      = (const int*)d_in[2];
    const float* emb      = (const float*)d_in[3];
    const float* Wp1      = (const float*)d_in[4];
    const float* bp1      = (const float*)d_in[5];
    const float* Ws1      = (const float*)d_in[6];
    const float* Wn1      = (const float*)d_in[7];
    const float* b1       = (const float*)d_in[8];
    const float* Wp2      = (const float*)d_in[9];
    const float* bp2      = (const float*)d_in[10];
    const float* Ws2      = (const float*)d_in[11];
    const float* Wn2      = (const float*)d_in[12];
    const float* b2       = (const float*)d_in[13];
    float* out = (float*)d_out;

    const int N = in_sizes[0];
    const int E = in_sizes[1];

    char* ws = (char*)d_ws;
    int* rp = (int*)ws;
    size_t off = (((size_t)(N + 1) * 4) + 255) & ~(size_t)255;
    ushort_t* Wpk  = (ushort_t*)(ws + off);              // 6 x 128x128 bf16
    ushort_t* h0   = Wpk + 6 * 16384;
    ushort_t* h1   = h0 + (size_t)N * HD;
    ushort_t* bufM = h1 + (size_t)N * HD;
    ushort_t* bufA = bufM + (size_t)N * HD;

    const int nbR = (N + 1 + 255) / 256;
    const int nbP = 6 * 64;
    const int nb_gemm = (N + 127) / 128;                 // 4 waves x 32 rows
    const int nb_seg  = (N + 3) / 4;                     // 1 node per wave

    k_prep<<<nbR + nbP, 256, 0, stream>>>(dst, E, rp, N,
                                          Wp1, Ws1, Wn1, Wp2, Ws2, Wn2, Wpk, nbR);

    const ushort_t* Wp1k = Wpk;
    const ushort_t* Ws1k = Wpk + 16384;
    const ushort_t* Wn1k = Wpk + 2 * 16384;
    const ushort_t* Wp2k = Wpk + 3 * 16384;
    const ushort_t* Ws2k = Wpk + 4 * 16384;
    const ushort_t* Wn2k = Wpk + 5 * 16384;

    // layer 1
    k_gather_pool<<<nb_gemm, 256, 0, stream>>>(node_ids, emb, Wp1k, bp1, h0, bufM, N);
    k_segmax<<<nb_seg, 256, 0, stream>>>(bufM, src, rp, bufA, N);
    k_dual<false><<<nb_gemm, 256, 0, stream>>>(h0, bufA, Ws1k, Wn1k, b1, h1, N);
    // layer 2
    k_pool<<<nb_gemm, 256, 0, stream>>>(h1, Wp2k, bp2, bufM, N);
    k_segmax<<<nb_seg, 256, 0, stream>>>(bufM, src, rp, bufA, N);
    k_dual<true><<<nb_gemm, 256, 0, stream>>>(h1, bufA, Ws2k, Wn2k, b2, out, N);
}

// Round 8
// 214.292 us; speedup vs baseline: 2.0747x; 1.0391x over previous
//
#include <hip/hip_runtime.h>

#define HD 128

typedef __attribute__((ext_vector_type(8))) short short8;   // 8 bf16
typedef __attribute__((ext_vector_type(4))) float floatx4;  // MFMA accumulator

typedef unsigned short ushort_t;
typedef unsigned int uint_t;

// ---------------------------------------------------------------- helpers ----
__device__ __forceinline__ ushort_t f2b(float f) {          // fp32 -> bf16 RNE
    union { float f; uint_t u; } v; v.f = f;
    uint_t r = v.u + 0x7fff + ((v.u >> 16) & 1);
    return (ushort_t)(r >> 16);
}
__device__ __forceinline__ float b_lo(uint_t p) {
    union { uint_t u; float f; } v; v.u = p << 16; return v.f;
}
__device__ __forceinline__ float b_hi(uint_t p) {
    union { uint_t u; float f; } v; v.u = p & 0xffff0000u; return v.f;
}
__device__ __forceinline__ uint_t packb(float a, float b) { // both bf16-exact
    union { float f; uint_t u; } x, y; x.f = a; y.f = b;
    return (x.u >> 16) | (y.u & 0xffff0000u);
}
__device__ __forceinline__ short8 cvt8(const float* __restrict__ p) {
    float4 u = *(const float4*)p, v = *(const float4*)(p + 4);
    short8 r;
    r[0] = (short)f2b(u.x); r[1] = (short)f2b(u.y); r[2] = (short)f2b(u.z); r[3] = (short)f2b(u.w);
    r[4] = (short)f2b(v.x); r[5] = (short)f2b(v.y); r[6] = (short)f2b(v.z); r[7] = (short)f2b(v.w);
    return r;
}

// ------------------------------------------------------------------ prep -----
// [0,nbR): rowptr (rp[i] = lower_bound(dst,i)); rest: W-pack to frag order.
// Frag map (identical for A- and B-operand): lane&15 -> non-K dim, quad*8+j -> K.
__global__ __launch_bounds__(256) void k_prep(const int* __restrict__ dst, int E,
                                              int* __restrict__ rp, int N,
                                              const float* W0, const float* W1,
                                              const float* W2, const float* W3,
                                              const float* W4, const float* W5,
                                              ushort_t* __restrict__ Wpk, int nbR) {
    int b = blockIdx.x;
    if (b < nbR) {
        int i = b * 256 + threadIdx.x;
        if (i > N) return;
        int lo = 0, hi = E;
        while (lo < hi) {
            int mid = (lo + hi) >> 1;
            if (dst[mid] < i) lo = mid + 1; else hi = mid;
        }
        rp[i] = lo;
    } else {
        int bb = b - nbR;
        const float* Ws[6] = {W0, W1, W2, W3, W4, W5};
        int mat = bb >> 6;
        int o = ((bb & 63) << 8) + threadIdx.x;
        int j = o & 7, l = (o >> 3) & 63, s = (o >> 9) & 3, t = o >> 11;
        int k = s * 32 + ((l >> 4) & 3) * 8 + j;
        int n = t * 16 + (l & 15);
        Wpk[(size_t)mat * 16384 + o] = f2b(Ws[mat][k * HD + n]);
    }
}

// ---------------------------------------------------------- W -> LDS stage ---
__device__ __forceinline__ void stage_w(const ushort_t* __restrict__ g,
                                        ushort_t* l, int tid) {
#pragma unroll
    for (int i = 0; i < 8; ++i) {
        int off = i * 2048 + tid * 8;
        *(short8*)&l[off] = *(const short8*)&g[off];
    }
}

// --------------------------------------------------------------- epilogue ----
// D = mfma(Wfrag, hfrag): lane&15 = h-row, quad*4+reg = output col within tile.
__device__ __forceinline__ void store_bf16(ushort_t* __restrict__ m, int row,
                                           int colbase, const floatx4& acc,
                                           const float4& bv, bool relu, int N) {
    if (row >= N) return;
    float v0 = acc[0] + bv.x, v1 = acc[1] + bv.y, v2 = acc[2] + bv.z, v3 = acc[3] + bv.w;
    if (relu) { v0 = fmaxf(v0, 0.f); v1 = fmaxf(v1, 0.f); v2 = fmaxf(v2, 0.f); v3 = fmaxf(v3, 0.f); }
    uint2 o; o.x = (uint_t)f2b(v0) | ((uint_t)f2b(v1) << 16);
    o.y = (uint_t)f2b(v2) | ((uint_t)f2b(v3) << 16);
    *(uint2*)&m[(size_t)row * HD + colbase] = o;
}

// ------------------------------------------------------ gather + pool GEMM ---
// h0 = bf16(emb[ids]);  m = relu(h0 @ Wp + b).  A loads overlap W staging.
__global__ __launch_bounds__(256) void k_gather_pool(const int* __restrict__ ids,
                                                     const float* __restrict__ emb,
                                                     const ushort_t* __restrict__ Wpk,
                                                     const float* __restrict__ bias,
                                                     ushort_t* __restrict__ h0,
                                                     ushort_t* __restrict__ m, int N) {
    __shared__ ushort_t Wl[16384];
    int wave = blockIdx.x * 4 + (threadIdx.x >> 6);
    int row0 = wave * 32;
    int l = threadIdx.x & 63;
    int ar0 = row0 + (l & 15); if (ar0 >= N) ar0 = N - 1;
    int ar1 = ar0 + 16;        if (ar1 >= N) ar1 = N - 1;
    int ac = (l >> 4) * 8;
    int id0 = ids[ar0], id1 = ids[ar1];
    short8 a0[4], a1[4];
#pragma unroll
    for (int s = 0; s < 4; ++s) {
        a0[s] = cvt8(&emb[(size_t)id0 * HD + s * 32 + ac]);
        a1[s] = cvt8(&emb[(size_t)id1 * HD + s * 32 + ac]);
    }
    stage_w(Wpk, Wl, threadIdx.x);
    __syncthreads();
    if (row0 >= N) return;
#pragma unroll
    for (int s = 0; s < 4; ++s) {
        *(short8*)&h0[(size_t)ar0 * HD + s * 32 + ac] = a0[s];
        *(short8*)&h0[(size_t)ar1 * HD + s * 32 + ac] = a1[s];
    }
    int g0 = row0 + (l & 15), g1 = g0 + 16;
    int cb0 = ((l >> 4) & 3) * 4;
#pragma unroll
    for (int t = 0; t < 8; ++t) {
        floatx4 acc0 = {0.f, 0.f, 0.f, 0.f};
        floatx4 acc1 = {0.f, 0.f, 0.f, 0.f};
#pragma unroll
        for (int s = 0; s < 4; ++s) {
            short8 w = *(const short8*)&Wl[(t * 4 + s) * 512 + l * 8];
            acc0 = __builtin_amdgcn_mfma_f32_16x16x32_bf16(w, a0[s], acc0, 0, 0, 0);
            acc1 = __builtin_amdgcn_mfma_f32_16x16x32_bf16(w, a1[s], acc1, 0, 0, 0);
        }
        int cb = t * 16 + cb0;
        float4 bv = *(const float4*)&bias[cb];
        store_bf16(m, g0, cb, acc0, bv, true, N);
        store_bf16(m, g1, cb, acc1, bv, true, N);
    }
}

// ----------------------------------------------------------- pool GEMM only --
__global__ __launch_bounds__(256) void k_pool(const ushort_t* __restrict__ h,
                                              const ushort_t* __restrict__ Wpk,
                                              const float* __restrict__ bias,
                                              ushort_t* __restrict__ m, int N) {
    __shared__ ushort_t Wl[16384];
    int wave = blockIdx.x * 4 + (threadIdx.x >> 6);
    int row0 = wave * 32;
    int l = threadIdx.x & 63;
    int ar0 = row0 + (l & 15); if (ar0 >= N) ar0 = N - 1;
    int ar1 = ar0 + 16;        if (ar1 >= N) ar1 = N - 1;
    int ac = (l >> 4) * 8;
    short8 a0[4], a1[4];
#pragma unroll
    for (int s = 0; s < 4; ++s) {
        a0[s] = *(const short8*)&h[(size_t)ar0 * HD + s * 32 + ac];
        a1[s] = *(const short8*)&h[(size_t)ar1 * HD + s * 32 + ac];
    }
    stage_w(Wpk, Wl, threadIdx.x);
    __syncthreads();
    if (row0 >= N) return;
    int g0 = row0 + (l & 15), g1 = g0 + 16;
    int cb0 = ((l >> 4) & 3) * 4;
#pragma unroll
    for (int t = 0; t < 8; ++t) {
        floatx4 acc0 = {0.f, 0.f, 0.f, 0.f};
        floatx4 acc1 = {0.f, 0.f, 0.f, 0.f};
#pragma unroll
        for (int s = 0; s < 4; ++s) {
            short8 w = *(const short8*)&Wl[(t * 4 + s) * 512 + l * 8];
            acc0 = __builtin_amdgcn_mfma_f32_16x16x32_bf16(w, a0[s], acc0, 0, 0, 0);
            acc1 = __builtin_amdgcn_mfma_f32_16x16x32_bf16(w, a1[s], acc1, 0, 0, 0);
        }
        int cb = t * 16 + cb0;
        float4 bv = *(const float4*)&bias[cb];
        store_bf16(m, g0, cb, acc0, bv, true, N);
        store_bf16(m, g1, cb, acc1, bv, true, N);
    }
}

// ---------------------------------------------------------------- segmax -----
// One node per wave. Per 64-edge chunk: ONE coalesced src load -> shfl
// distribution; 16 clamped edges per batch with all 4 row-loads in flight
// (clamp duplicates are idempotent under max). No serial tail.
__global__ __launch_bounds__(256) void k_segmax(const ushort_t* __restrict__ m,
                                                const int* __restrict__ src,
                                                const int* __restrict__ rp,
                                                ushort_t* __restrict__ agg, int N) {
    int node = blockIdx.x * 4 + (threadIdx.x >> 6);
    if (node >= N) return;
    int l = threadIdx.x & 63;
    int slot = l >> 4;                 // 0..3 edge slot
    int col8 = (l & 15) * 8;           // 8 bf16 (16 B) per lane
    int beg = rp[node], end = rp[node + 1];
    float a[8] = {0.f, 0.f, 0.f, 0.f, 0.f, 0.f, 0.f, 0.f};
    float c[8] = {0.f, 0.f, 0.f, 0.f, 0.f, 0.f, 0.f, 0.f};
    for (int base = beg; base < end; base += 64) {
        int nb = end - base; if (nb > 64) nb = 64;
        int si = base + l; if (si > end - 1) si = end - 1;
        int sv = src[si];              // coalesced: 64 edge indices per wave
        for (int o = 0; o < nb; o += 16) {
            int last = nb - 1;
            int i0 = o + slot;      if (i0 > last) i0 = last;
            int i1 = o + 4 + slot;  if (i1 > last) i1 = last;
            int i2 = o + 8 + slot;  if (i2 > last) i2 = last;
            int i3 = o + 12 + slot; if (i3 > last) i3 = last;
            int s0 = __shfl(sv, i0), s1 = __shfl(sv, i1);
            int s2 = __shfl(sv, i2), s3 = __shfl(sv, i3);
            uint4 p0 = *(const uint4*)&m[(size_t)s0 * HD + col8];
            uint4 p1 = *(const uint4*)&m[(size_t)s1 * HD + col8];
            uint4 p2 = *(const uint4*)&m[(size_t)s2 * HD + col8];
            uint4 p3 = *(const uint4*)&m[(size_t)s3 * HD + col8];
            a[0] = fmaxf(a[0], b_lo(p0.x)); a[1] = fmaxf(a[1], b_hi(p0.x));
            a[2] = fmaxf(a[2], b_lo(p0.y)); a[3] = fmaxf(a[3], b_hi(p0.y));
            a[4] = fmaxf(a[4], b_lo(p0.z)); a[5] = fmaxf(a[5], b_hi(p0.z));
            a[6] = fmaxf(a[6], b_lo(p0.w)); a[7] = fmaxf(a[7], b_hi(p0.w));
            c[0] = fmaxf(c[0], b_lo(p1.x)); c[1] = fmaxf(c[1], b_hi(p1.x));
            c[2] = fmaxf(c[2], b_lo(p1.y)); c[3] = fmaxf(c[3], b_hi(p1.y));
            c[4] = fmaxf(c[4], b_lo(p1.z)); c[5] = fmaxf(c[5], b_hi(p1.z));
            c[6] = fmaxf(c[6], b_lo(p1.w)); c[7] = fmaxf(c[7], b_hi(p1.w));
            a[0] = fmaxf(a[0], b_lo(p2.x)); a[1] = fmaxf(a[1], b_hi(p2.x));
            a[2] = fmaxf(a[2], b_lo(p2.y)); a[3] = fmaxf(a[3], b_hi(p2.y));
            a[4] = fmaxf(a[4], b_lo(p2.z)); a[5] = fmaxf(a[5], b_hi(p2.z));
            a[6] = fmaxf(a[6], b_lo(p2.w)); a[7] = fmaxf(a[7], b_hi(p2.w));
            c[0] = fmaxf(c[0], b_lo(p3.x)); c[1] = fmaxf(c[1], b_hi(p3.x));
            c[2] = fmaxf(c[2], b_lo(p3.y)); c[3] = fmaxf(c[3], b_hi(p3.y));
            c[4] = fmaxf(c[4], b_lo(p3.z)); c[5] = fmaxf(c[5], b_hi(p3.z));
            c[6] = fmaxf(c[6], b_lo(p3.w)); c[7] = fmaxf(c[7], b_hi(p3.w));
        }
    }
#pragma unroll
    for (int i = 0; i < 8; ++i) {
        a[i] = fmaxf(a[i], c[i]);
        a[i] = fmaxf(a[i], __shfl_xor(a[i], 16));
        a[i] = fmaxf(a[i], __shfl_xor(a[i], 32));
    }
    if (slot == 0) {
        uint4 o;
        o.x = packb(a[0], a[1]); o.y = packb(a[2], a[3]);
        o.z = packb(a[4], a[5]); o.w = packb(a[6], a[7]);
        *(uint4*)&agg[(size_t)node * HD + col8] = o;
    }
}

// ----------------------------------------------------------- dual GEMM -------
// out = h @ Wself + agg @ Wneigh + b; A/agg loads overlap W staging.
template <bool F32OUT>
__global__ __launch_bounds__(256) void k_dual(const ushort_t* __restrict__ h,
                                              const ushort_t* __restrict__ agg,
                                              const ushort_t* __restrict__ WsPk,
                                              const ushort_t* __restrict__ WnPk,
                                              const float* __restrict__ bias,
                                              void* __restrict__ outp, int N) {
    __shared__ ushort_t Wl[32768];                       // Ws | Wn
    int wave = blockIdx.x * 4 + (threadIdx.x >> 6);
    int row0 = wave * 32;
    int l = threadIdx.x & 63;
    int ar0 = row0 + (l & 15); if (ar0 >= N) ar0 = N - 1;
    int ar1 = ar0 + 16;        if (ar1 >= N) ar1 = N - 1;
    int ac = (l >> 4) * 8;
    short8 ah0[4], ah1[4], ag0[4], ag1[4];
#pragma unroll
    for (int s = 0; s < 4; ++s) {
        ah0[s] = *(const short8*)&h[(size_t)ar0 * HD + s * 32 + ac];
        ah1[s] = *(const short8*)&h[(size_t)ar1 * HD + s * 32 + ac];
        ag0[s] = *(const short8*)&agg[(size_t)ar0 * HD + s * 32 + ac];
        ag1[s] = *(const short8*)&agg[(size_t)ar1 * HD + s * 32 + ac];
    }
    stage_w(WsPk, Wl, threadIdx.x);
    stage_w(WnPk, Wl + 16384, threadIdx.x);
    __syncthreads();
    if (row0 >= N) return;
    int g0 = row0 + (l & 15), g1 = g0 + 16;
    int cb0 = ((l >> 4) & 3) * 4;
#pragma unroll
    for (int t = 0; t < 8; ++t) {
        floatx4 acc0 = {0.f, 0.f, 0.f, 0.f};
        floatx4 acc1 = {0.f, 0.f, 0.f, 0.f};
#pragma unroll
        for (int s = 0; s < 4; ++s) {
            short8 ws = *(const short8*)&Wl[(t * 4 + s) * 512 + l * 8];
            acc0 = __builtin_amdgcn_mfma_f32_16x16x32_bf16(ws, ah0[s], acc0, 0, 0, 0);
            acc1 = __builtin_amdgcn_mfma_f32_16x16x32_bf16(ws, ah1[s], acc1, 0, 0, 0);
        }
#pragma unroll
        for (int s = 0; s < 4; ++s) {
            short8 wn = *(const short8*)&Wl[16384 + (t * 4 + s) * 512 + l * 8];
            acc0 = __builtin_amdgcn_mfma_f32_16x16x32_bf16(wn, ag0[s], acc0, 0, 0, 0);
            acc1 = __builtin_amdgcn_mfma_f32_16x16x32_bf16(wn, ag1[s], acc1, 0, 0, 0);
        }
        int cb = t * 16 + cb0;
        float4 bv = *(const float4*)&bias[cb];
        if (F32OUT) {
            float* out = (float*)outp;
            if (g0 < N) {
                float4 v = make_float4(acc0[0] + bv.x, acc0[1] + bv.y,
                                       acc0[2] + bv.z, acc0[3] + bv.w);
                *(float4*)&out[(size_t)g0 * HD + cb] = v;
            }
            if (g1 < N) {
                float4 v = make_float4(acc1[0] + bv.x, acc1[1] + bv.y,
                                       acc1[2] + bv.z, acc1[3] + bv.w);
                *(float4*)&out[(size_t)g1 * HD + cb] = v;
            }
        } else {
            ushort_t* out = (ushort_t*)outp;
            store_bf16(out, g0, cb, acc0, bv, false, N);
            store_bf16(out, g1, cb, acc1, bv, false, N);
        }
    }
}

// ---------------------------------------------------------------- launch -----
extern "C" void kernel_launch(void* const* d_in, const int* in_sizes, int n_in,
                              void* d_out, int out_size, void* d_ws, size_t ws_size,
                              hipStream_t stream) {
    const int*   node_ids = (const int*)d_in[0];
    const int*   src      = (const int*)d_in[1];
    const int*   dst      = (const int*)d_in[2];
    const float* emb      = (const float*)d_in[3];
    const float* Wp1      = (const float*)d_in[4];
    const float* bp1      = (const float*)d_in[5];
    const float* Ws1      = (const float*)d_in[6];
    const float* Wn1      = (const float*)d_in[7];
    const float* b1       = (const float*)d_in[8];
    const float* Wp2      = (const float*)d_in[9];
    const float* bp2      = (const float*)d_in[10];
    const float* Ws2      = (const float*)d_in[11];
    const float* Wn2      = (const float*)d_in[12];
    const float* b2       = (const float*)d_in[13];
    float* out = (float*)d_out;

    const int N = in_sizes[0];
    const int E = in_sizes[1];

    char* ws = (char*)d_ws;
    int* rp = (int*)ws;
    size_t off = (((size_t)(N + 1) * 4) + 255) & ~(size_t)255;
    ushort_t* Wpk  = (ushort_t*)(ws + off);              // 6 x 128x128 bf16
    ushort_t* h0   = Wpk + 6 * 16384;
    ushort_t* h1   = h0 + (size_t)N * HD;
    ushort_t* bufM = h1 + (size_t)N * HD;
    ushort_t* bufA = bufM + (size_t)N * HD;

    const int nbR = (N + 1 + 255) / 256;
    const int nbP = 6 * 64;
    const int nb_gemm = (N + 127) / 128;                 // 4 waves x 32 rows
    const int nb_seg  = (N + 3) / 4;                     // 1 node per wave

    k_prep<<<nbR + nbP, 256, 0, stream>>>(dst, E, rp, N,
                                          Wp1, Ws1, Wn1, Wp2, Ws2, Wn2, Wpk, nbR);

    const ushort_t* Wp1k = Wpk;
    const ushort_t* Ws1k = Wpk + 16384;
    const ushort_t* Wn1k = Wpk + 2 * 16384;
    const ushort_t* Wp2k = Wpk + 3 * 16384;
    const ushort_t* Ws2k = Wpk + 4 * 16384;
    const ushort_t* Wn2k = Wpk + 5 * 16384;

    // layer 1
    k_gather_pool<<<nb_gemm, 256, 0, stream>>>(node_ids, emb, Wp1k, bp1, h0, bufM, N);
    k_segmax<<<nb_seg, 256, 0, stream>>>(bufM, src, rp, bufA, N);
    k_dual<false><<<nb_gemm, 256, 0, stream>>>(h0, bufA, Ws1k, Wn1k, b1, h1, N);
    // layer 2
    k_pool<<<nb_gemm, 256, 0, stream>>>(h1, Wp2k, bp2, bufM, N);
    k_segmax<<<nb_seg, 256, 0, stream>>>(bufM, src, rp, bufA, N);
    k_dual<true><<<nb_gemm, 256, 0, stream>>>(h1, bufA, Ws2k, Wn2k, b2, out, N);
}